// Round 1
// baseline (3757.677 us; speedup 1.0000x reference)
//
#include <hip/hip_runtime.h>
#include <math.h>

typedef __bf16 bf16;
typedef float f32x4 __attribute__((ext_vector_type(4)));
typedef bf16  bf16x4 __attribute__((ext_vector_type(4)));
typedef bf16  bf16x8 __attribute__((ext_vector_type(8)));

#define N_B  64
#define N_L  256
#define N_H  16
#define N_D  2048
#define N_HD 128
#define M_TOT (N_B * N_L)   // 16384

static __device__ __forceinline__ float bfbits_lo(unsigned u) {
  union { unsigned u; float f; } c; c.u = u << 16; return c.f;
}
static __device__ __forceinline__ float bfbits_hi(unsigned u) {
  union { unsigned u; float f; } c; c.u = u & 0xffff0000u; return c.f;
}

// ---------------- prep kernels ----------------
__global__ void k_cast_x(const float* __restrict__ x, bf16* __restrict__ xb, int n4) {
  int i = blockIdx.x * blockDim.x + threadIdx.x;
  int st = gridDim.x * blockDim.x;
  for (; i < n4; i += st) {
    float4 v = ((const float4*)x)[i];
    bf16x4 o;
    o[0] = (bf16)v.x; o[1] = (bf16)v.y; o[2] = (bf16)v.z; o[3] = (bf16)v.w;
    ((bf16x4*)xb)[i] = o;
  }
}

__global__ void k_transpose_w(const float* __restrict__ w, bf16* __restrict__ wt) {
  __shared__ float t[32][33];
  int n0 = blockIdx.x * 32, k0 = blockIdx.y * 32;
  t[threadIdx.y][threadIdx.x] = w[(size_t)(k0 + threadIdx.y) * N_D + n0 + threadIdx.x];
  __syncthreads();
  wt[(size_t)(n0 + threadIdx.y) * N_D + k0 + threadIdx.x] = (bf16)t[threadIdx.x][threadIdx.y];
}

__global__ void k_trig(float2* __restrict__ tab) {
  int idx = blockIdx.x * blockDim.x + threadIdx.x;
  if (idx < N_L * (N_HD / 2)) {
    int l = idx >> 6, i = idx & 63;
    float ang = (float)l * powf(10000.0f, -(float)(2 * i) / 128.0f);
    tab[idx].x = cosf(ang);
    tab[idx].y = sinf(ang);
  }
}

__global__ void k_rope(bf16* __restrict__ Qp, bf16* __restrict__ Kp,
                       const float2* __restrict__ tab) {
  const int npp = M_TOT * N_D / 2;   // pairs per tensor
  int i = blockIdx.x * blockDim.x + threadIdx.x;
  int st = gridDim.x * blockDim.x;
  for (; i < 2 * npp; i += st) {
    bf16* p; int rem;
    if (i < npp) { p = Qp; rem = i; } else { p = Kp; rem = i - npp; }
    int fi = rem & 63;
    int l = (rem >> 6) & 255;
    float2 cs = tab[(l << 6) | fi];
    unsigned* pu = (unsigned*)(p + (size_t)rem * 2);
    unsigned u = *pu;
    float x1 = bfbits_lo(u), x2 = bfbits_hi(u);
    float ev = x1 * cs.x - x2 * cs.y;
    float od = x2 * cs.x + x1 * cs.y;
    bf16 pr[2]; pr[0] = (bf16)ev; pr[1] = (bf16)od;
    *pu = *(unsigned*)pr;
  }
}

// ---------------- MFMA GEMM: C[m][n] = sum_k A[m][k] * BT[n][k] + bias[n] ----------------
// MODE 0: write bf16 to [b][h][l][d] (QKV).  MODE 1: write fp32 row-major to d_out.
template<int MODE>
__global__ __launch_bounds__(256) void k_gemm(
    const bf16* __restrict__ A, const bf16* __restrict__ BT,
    const float* __restrict__ bias, void* __restrict__ dstv)
{
  __shared__ bf16 As[128][32];
  __shared__ bf16 Bs[128][32];
  const int m0 = blockIdx.x * 128;
  const int n0 = blockIdx.y * 128;
  const int tid = threadIdx.x;
  const int wave = tid >> 6, lane = tid & 63;
  const int wr = wave >> 1, wc = wave & 1;
  const int lr = lane & 15, lg = lane >> 4;
  const int srow = lane >> 2;          // row within 16-row staging chunk
  const int scol = (lane & 3) * 8;     // elem offset within row

  f32x4 acc[4][4];
#pragma unroll
  for (int i = 0; i < 4; ++i)
#pragma unroll
    for (int j = 0; j < 4; ++j)
      acc[i][j] = (f32x4){0.f, 0.f, 0.f, 0.f};

  for (int k0 = 0; k0 < N_D; k0 += 32) {
#pragma unroll
    for (int t = 0; t < 2; ++t) {
      const int c = wave * 2 + t;               // chunk 0..7 (16 rows each)
      const int row = c * 16 + srow;
      const bf16* gA = A + (size_t)(m0 + row) * N_D + k0 + scol;
      __builtin_amdgcn_global_load_lds(
          (const __attribute__((address_space(1))) void*)gA,
          (__attribute__((address_space(3))) void*)&As[c * 16][0], 16, 0, 0);
      const bf16* gB = BT + (size_t)(n0 + row) * N_D + k0 + scol;
      __builtin_amdgcn_global_load_lds(
          (const __attribute__((address_space(1))) void*)gB,
          (__attribute__((address_space(3))) void*)&Bs[c * 16][0], 16, 0, 0);
    }
    __syncthreads();
    bf16x8 af[4], bfr[4];
#pragma unroll
    for (int i = 0; i < 4; ++i) {
      const bf16x4* pa = (const bf16x4*)&As[wr * 64 + i * 16 + lr][lg * 4];
      af[i] = __builtin_shufflevector(pa[0], pa[4], 0, 1, 2, 3, 4, 5, 6, 7);
      const bf16x4* pb = (const bf16x4*)&Bs[wc * 64 + i * 16 + lr][lg * 4];
      bfr[i] = __builtin_shufflevector(pb[0], pb[4], 0, 1, 2, 3, 4, 5, 6, 7);
    }
#pragma unroll
    for (int i = 0; i < 4; ++i)
#pragma unroll
      for (int j = 0; j < 4; ++j)
        acc[i][j] = __builtin_amdgcn_mfma_f32_16x16x32_bf16(af[i], bfr[j], acc[i][j], 0, 0, 0);
    __syncthreads();
  }

#pragma unroll
  for (int i = 0; i < 4; ++i) {
#pragma unroll
    for (int r = 0; r < 4; ++r) {
      const int m = m0 + wr * 64 + i * 16 + lg * 4 + r;
#pragma unroll
      for (int j = 0; j < 4; ++j) {
        const int n = n0 + wc * 64 + j * 16 + lr;
        float v = acc[i][j][r] + bias[n];
        if (MODE == 0) {
          bf16* dst = (bf16*)dstv;
          const int b = m >> 8, l = m & 255;
          const int h = n >> 7, d = n & 127;
          dst[(((size_t)b * N_H + h) * N_L + l) * N_HD + d] = (bf16)v;
        } else {
          float* dst = (float*)dstv;
          dst[(size_t)m * N_D + n] = v;
        }
      }
    }
  }
}

// ---------------- attention: one block per (b,h) ----------------
__global__ __launch_bounds__(256) void k_attn(
    const bf16* __restrict__ Q, const bf16* __restrict__ K,
    const bf16* __restrict__ V, bf16* __restrict__ O)
{
  __shared__ bf16 Kt[128][256];   // K transposed [d][j]
  __shared__ bf16 Vt[128][258];   // V transposed [d][j], +2 pad (bank decorrelation)
  __shared__ float P[4][256];     // per-wave softmax numerators
  __shared__ float Qrow[4][128];  // 4 query rows in f32

  const int bh = blockIdx.x;
  const int b = bh >> 4, h = bh & 15;
  const int tid = threadIdx.x, wave = tid >> 6, lane = tid & 63;
  const bf16* Qg = Q + (size_t)bh * N_L * N_HD;
  const bf16* Kg = K + (size_t)bh * N_L * N_HD;
  const bf16* Vg = V + (size_t)bh * N_L * N_HD;

  for (int e8 = tid * 8; e8 < N_L * N_HD; e8 += 256 * 8) {
    uint4 kv = *(const uint4*)(Kg + e8);
    uint4 vv = *(const uint4*)(Vg + e8);
    int j = e8 >> 7, d = e8 & 127;
    bf16 tk[8]; *(uint4*)tk = kv;
    bf16 tv[8]; *(uint4*)tv = vv;
#pragma unroll
    for (int u = 0; u < 8; ++u) { Kt[d + u][j] = tk[u]; Vt[d + u][j] = tv[u]; }
  }

  const float scale = 0.08838834764831843f;  // 1/sqrt(128)

  for (int it = 0; it < 64; ++it) {
    __syncthreads();                    // Kt/Vt ready (it=0); Qrow consumers done
    for (int e = tid; e < 512; e += 256) {
      int r = e >> 7, d = e & 127;
      Qrow[r][d] = (float)Qg[(size_t)(it * 4 + r) * N_HD + d];
    }
    __syncthreads();
    const int q = it * 4 + wave;
    float a0 = 0.f, a1 = 0.f, a2 = 0.f, a3 = 0.f;
#pragma unroll 4
    for (int d = 0; d < 128; ++d) {
      float qd = Qrow[wave][d];
      uint2 kk = *(const uint2*)&Kt[d][lane * 4];
      a0 = fmaf(qd, bfbits_lo(kk.x), a0);
      a1 = fmaf(qd, bfbits_hi(kk.x), a1);
      a2 = fmaf(qd, bfbits_lo(kk.y), a2);
      a3 = fmaf(qd, bfbits_hi(kk.y), a3);
    }
    const int jb = lane * 4;
    float s0 = (jb + 0 <= q) ? a0 * scale : -INFINITY;
    float s1 = (jb + 1 <= q) ? a1 * scale : -INFINITY;
    float s2 = (jb + 2 <= q) ? a2 * scale : -INFINITY;
    float s3 = (jb + 3 <= q) ? a3 * scale : -INFINITY;
    float mx = fmaxf(fmaxf(s0, s1), fmaxf(s2, s3));
    for (int off = 32; off > 0; off >>= 1) mx = fmaxf(mx, __shfl_xor(mx, off));
    float e0 = __expf(s0 - mx), e1 = __expf(s1 - mx);
    float e2 = __expf(s2 - mx), e3 = __expf(s3 - mx);
    float sm = e0 + e1 + e2 + e3;
    for (int off = 32; off > 0; off >>= 1) sm += __shfl_xor(sm, off);
    *(float4*)&P[wave][jb] = make_float4(e0, e1, e2, e3);
    __syncthreads();
    float acc0 = 0.f, acc1 = 0.f;
    const int nj4 = (q >> 2) + 1;       // groups of 4 keys; zeros beyond q
    for (int j4 = 0; j4 < nj4; ++j4) {
      float4 p4 = *(const float4*)&P[wave][j4 * 4];
      unsigned v00 = *(const unsigned*)&Vt[lane][j4 * 4];
      unsigned v01 = *(const unsigned*)&Vt[lane][j4 * 4 + 2];
      unsigned v10 = *(const unsigned*)&Vt[lane + 64][j4 * 4];
      unsigned v11 = *(const unsigned*)&Vt[lane + 64][j4 * 4 + 2];
      acc0 += p4.x * bfbits_lo(v00) + p4.y * bfbits_hi(v00)
            + p4.z * bfbits_lo(v01) + p4.w * bfbits_hi(v01);
      acc1 += p4.x * bfbits_lo(v10) + p4.y * bfbits_hi(v10)
            + p4.z * bfbits_lo(v11) + p4.w * bfbits_hi(v11);
    }
    float inv = 1.0f / sm;
    acc0 *= inv; acc1 *= inv;
    size_t ob = (((size_t)b * N_L + q) * N_H + h) * N_HD;
    O[ob + lane] = (bf16)acc0;
    O[ob + lane + 64] = (bf16)acc1;
  }
}

// ---------------- launch ----------------
extern "C" void kernel_launch(void* const* d_in, const int* in_sizes, int n_in,
                              void* d_out, int out_size, void* d_ws, size_t ws_size,
                              hipStream_t stream) {
  const float* x  = (const float*)d_in[0];
  const float* wq = (const float*)d_in[1];
  const float* bq = (const float*)d_in[2];
  const float* wk = (const float*)d_in[3];
  const float* bk = (const float*)d_in[4];
  const float* wv = (const float*)d_in[5];
  const float* bv = (const float*)d_in[6];
  const float* wo = (const float*)d_in[7];
  const float* bo = (const float*)d_in[8];

  char* ws = (char*)d_ws;
  const size_t WSZ = (size_t)N_D * N_D * sizeof(bf16);    // 8 MB per transposed weight
  const size_t XSZ = (size_t)M_TOT * N_D * sizeof(bf16);  // 64 MB per activation tensor
  bf16* wqT = (bf16*)(ws);
  bf16* wkT = (bf16*)(ws + WSZ);
  bf16* wvT = (bf16*)(ws + 2 * WSZ);
  bf16* woT = (bf16*)(ws + 3 * WSZ);
  bf16* xb  = (bf16*)(ws + 4 * WSZ);
  bf16* Qb  = (bf16*)(ws + 4 * WSZ + XSZ);
  bf16* Kb  = (bf16*)(ws + 4 * WSZ + 2 * XSZ);
  bf16* Vb  = (bf16*)(ws + 4 * WSZ + 3 * XSZ);
  bf16* Ob  = (bf16*)(ws + 4 * WSZ + 4 * XSZ);
  float2* tab = (float2*)(ws + 4 * WSZ + 5 * XSZ);

  k_cast_x<<<2048, 256, 0, stream>>>(x, xb, M_TOT * N_D / 4);
  dim3 tb(32, 32), tg(64, 64);
  k_transpose_w<<<tg, tb, 0, stream>>>(wq, wqT);
  k_transpose_w<<<tg, tb, 0, stream>>>(wk, wkT);
  k_transpose_w<<<tg, tb, 0, stream>>>(wv, wvT);
  k_transpose_w<<<tg, tb, 0, stream>>>(wo, woT);
  k_trig<<<64, 256, 0, stream>>>(tab);

  dim3 gg(128, 16);
  k_gemm<0><<<gg, 256, 0, stream>>>(xb, wqT, bq, Qb);
  k_gemm<0><<<gg, 256, 0, stream>>>(xb, wkT, bk, Kb);
  k_gemm<0><<<gg, 256, 0, stream>>>(xb, wvT, bv, Vb);

  k_rope<<<4096, 256, 0, stream>>>(Qb, Kb, tab);
  k_attn<<<1024, 256, 0, stream>>>(Qb, Kb, Vb, Ob);
  k_gemm<1><<<gg, 256, 0, stream>>>(Ob, woT, bo, d_out);
}

// Round 3
// 2175.588 us; speedup vs baseline: 1.7272x; 1.7272x over previous
//
#include <hip/hip_runtime.h>
#include <math.h>

typedef __bf16 bf16;
typedef float f32x4 __attribute__((ext_vector_type(4)));
typedef bf16  bf16x4 __attribute__((ext_vector_type(4)));
typedef bf16  bf16x8 __attribute__((ext_vector_type(8)));

#define N_B  64
#define N_L  256
#define N_H  16
#define N_D  2048
#define N_HD 128
#define M_TOT (N_B * N_L)   // 16384

static __device__ __forceinline__ float bfbits_lo(unsigned u) {
  union { unsigned u; float f; } c; c.u = u << 16; return c.f;
}
static __device__ __forceinline__ float bfbits_hi(unsigned u) {
  union { unsigned u; float f; } c; c.u = u & 0xffff0000u; return c.f;
}

static __device__ __forceinline__ f32x4 shflx4(f32x4 v, int m) {
  f32x4 r;
  r[0] = __shfl_xor(v[0], m);
  r[1] = __shfl_xor(v[1], m);
  r[2] = __shfl_xor(v[2], m);
  r[3] = __shfl_xor(v[3], m);
  return r;
}
static __device__ __forceinline__ f32x4 max4(f32x4 a, f32x4 b) {
  f32x4 r;
  r[0] = fmaxf(a[0], b[0]); r[1] = fmaxf(a[1], b[1]);
  r[2] = fmaxf(a[2], b[2]); r[3] = fmaxf(a[3], b[3]);
  return r;
}

// ---------------- prep kernels ----------------
__global__ void k_cast_x(const float* __restrict__ x, bf16* __restrict__ xb, int n4) {
  int i = blockIdx.x * blockDim.x + threadIdx.x;
  int st = gridDim.x * blockDim.x;
  for (; i < n4; i += st) {
    float4 v = ((const float4*)x)[i];
    bf16x4 o;
    o[0] = (bf16)v.x; o[1] = (bf16)v.y; o[2] = (bf16)v.z; o[3] = (bf16)v.w;
    ((bf16x4*)xb)[i] = o;
  }
}

__global__ void k_transpose_w(const float* __restrict__ w, bf16* __restrict__ wt) {
  __shared__ float t[32][33];
  int n0 = blockIdx.x * 32, k0 = blockIdx.y * 32;
  t[threadIdx.y][threadIdx.x] = w[(size_t)(k0 + threadIdx.y) * N_D + n0 + threadIdx.x];
  __syncthreads();
  wt[(size_t)(n0 + threadIdx.y) * N_D + k0 + threadIdx.x] = (bf16)t[threadIdx.x][threadIdx.y];
}

__global__ void k_trig(float2* __restrict__ tab) {
  int idx = blockIdx.x * blockDim.x + threadIdx.x;
  if (idx < N_L * (N_HD / 2)) {
    int l = idx >> 6, i = idx & 63;
    float ang = (float)l * powf(10000.0f, -(float)(2 * i) / 128.0f);
    tab[idx].x = cosf(ang);
    tab[idx].y = sinf(ang);
  }
}

__global__ void k_rope(bf16* __restrict__ Qp, bf16* __restrict__ Kp,
                       const float2* __restrict__ tab) {
  const int npp = M_TOT * N_D / 2;   // pairs per tensor
  int i = blockIdx.x * blockDim.x + threadIdx.x;
  int st = gridDim.x * blockDim.x;
  for (; i < 2 * npp; i += st) {
    bf16* p; int rem;
    if (i < npp) { p = Qp; rem = i; } else { p = Kp; rem = i - npp; }
    int fi = rem & 63;
    int l = (rem >> 6) & 255;
    float2 cs = tab[(l << 6) | fi];
    unsigned* pu = (unsigned*)(p + (size_t)rem * 2);
    unsigned u = *pu;
    float x1 = bfbits_lo(u), x2 = bfbits_hi(u);
    float ev = x1 * cs.x - x2 * cs.y;
    float od = x2 * cs.x + x1 * cs.y;
    bf16 pr[2]; pr[0] = (bf16)ev; pr[1] = (bf16)od;
    *pu = *(unsigned*)pr;
  }
}

// ---------------- MFMA GEMM: C[m][n] = sum_k A[m][k] * BT[n][k] + bias[n] ----------------
// MODE 0: bf16 to [b][h][l][d] (Q,K).  MODE 1: fp32 row-major (final out).
// MODE 2: bf16 to [b][h][d][l]  (V transposed, for attention PV fragments).
template<int MODE>
__global__ __launch_bounds__(256) void k_gemm(
    const bf16* __restrict__ A, const bf16* __restrict__ BT,
    const float* __restrict__ bias, void* __restrict__ dstv)
{
  __shared__ bf16 As[128][32];
  __shared__ bf16 Bs[128][32];
  const int m0 = blockIdx.x * 128;
  const int n0 = blockIdx.y * 128;
  const int tid = threadIdx.x;
  const int wave = tid >> 6, lane = tid & 63;
  const int wr = wave >> 1, wc = wave & 1;
  const int lr = lane & 15, lg = lane >> 4;
  const int srow = lane >> 2;          // row within 16-row staging chunk
  const int scol = (lane & 3) * 8;     // elem offset within row

  f32x4 acc[4][4];
#pragma unroll
  for (int i = 0; i < 4; ++i)
#pragma unroll
    for (int j = 0; j < 4; ++j)
      acc[i][j] = (f32x4){0.f, 0.f, 0.f, 0.f};

  for (int k0 = 0; k0 < N_D; k0 += 32) {
#pragma unroll
    for (int t = 0; t < 2; ++t) {
      const int c = wave * 2 + t;               // chunk 0..7 (16 rows each)
      const int row = c * 16 + srow;
      const bf16* gA = A + (size_t)(m0 + row) * N_D + k0 + scol;
      __builtin_amdgcn_global_load_lds(
          (const __attribute__((address_space(1))) void*)gA,
          (__attribute__((address_space(3))) void*)&As[c * 16][0], 16, 0, 0);
      const bf16* gB = BT + (size_t)(n0 + row) * N_D + k0 + scol;
      __builtin_amdgcn_global_load_lds(
          (const __attribute__((address_space(1))) void*)gB,
          (__attribute__((address_space(3))) void*)&Bs[c * 16][0], 16, 0, 0);
    }
    __syncthreads();
    bf16x8 af[4], bfr[4];
#pragma unroll
    for (int i = 0; i < 4; ++i) {
      const bf16x4* pa = (const bf16x4*)&As[wr * 64 + i * 16 + lr][lg * 4];
      af[i] = __builtin_shufflevector(pa[0], pa[4], 0, 1, 2, 3, 4, 5, 6, 7);
      const bf16x4* pb = (const bf16x4*)&Bs[wc * 64 + i * 16 + lr][lg * 4];
      bfr[i] = __builtin_shufflevector(pb[0], pb[4], 0, 1, 2, 3, 4, 5, 6, 7);
    }
#pragma unroll
    for (int i = 0; i < 4; ++i)
#pragma unroll
      for (int j = 0; j < 4; ++j)
        acc[i][j] = __builtin_amdgcn_mfma_f32_16x16x32_bf16(af[i], bfr[j], acc[i][j], 0, 0, 0);
    __syncthreads();
  }

#pragma unroll
  for (int i = 0; i < 4; ++i) {
#pragma unroll
    for (int r = 0; r < 4; ++r) {
      const int m = m0 + wr * 64 + i * 16 + lg * 4 + r;
#pragma unroll
      for (int j = 0; j < 4; ++j) {
        const int n = n0 + wc * 64 + j * 16 + lr;
        float v = acc[i][j][r] + bias[n];
        if (MODE == 0) {
          bf16* dst = (bf16*)dstv;
          const int b = m >> 8, l = m & 255;
          const int h = n >> 7, d = n & 127;
          dst[(((size_t)b * N_H + h) * N_L + l) * N_HD + d] = (bf16)v;
        } else if (MODE == 2) {
          bf16* dst = (bf16*)dstv;
          const int b = m >> 8, l = m & 255;
          const int h = n >> 7, d = n & 127;
          dst[(((size_t)b * N_H + h) * N_HD + d) * N_L + l] = (bf16)v;
        } else {
          float* dst = (float*)dstv;
          dst[(size_t)m * N_D + n] = v;
        }
      }
    }
  }
}

// ---------------- MFMA flash attention: one block per (b,h), 8 waves ----------------
// Q,K in [b][h][l][d] (RoPE applied). Vt in [b][h][d][l]. O to [b][l][h][d].
// Wave w handles q-blocks {w, 15-w} (16 rows each) -> 9 j-steps per wave, balanced.
// K staged swizzled in LDS (64KB) via global_load_lds with pre-swizzled source.
// V fragments read directly from global (L2-resident). P via small per-wave LDS.
__global__ __launch_bounds__(512) void k_attn_mfma(
    const bf16* __restrict__ Q, const bf16* __restrict__ K,
    const bf16* __restrict__ Vt, bf16* __restrict__ O)
{
  __shared__ bf16 Kl[N_L * N_HD];   // 64KB; row j = 256B = 16 granules; granule g holds src granule g^(j&7)
  __shared__ bf16 Pl[8][16][56];    // per-wave P staging; 112B row stride (16B aligned, bank-balanced)

  const int bh = blockIdx.x;
  const int b = bh >> 4, h = bh & 15;
  const int tid = threadIdx.x;
  const int wave = tid >> 6, lane = tid & 63;
  const int c = lane & 15, g8 = lane >> 4;

  const bf16* Qg = Q + (size_t)bh * (N_L * N_HD);
  const bf16* Kg = K + (size_t)bh * (N_L * N_HD);
  const bf16* Vg = Vt + (size_t)bh * (N_L * N_HD);

  // ---- stage K into LDS, XOR-swizzled via pre-swizzled global source ----
#pragma unroll
  for (int t = 0; t < 8; ++t) {
    int idx = tid + 512 * t;            // 16B-granule index, 4096 total
    int row = idx >> 4, g = idx & 15;
    const bf16* src = Kg + row * N_HD + ((g ^ (row & 7)) << 3);
    __builtin_amdgcn_global_load_lds(
        (const __attribute__((address_space(1))) void*)src,
        (__attribute__((address_space(3))) void*)(Kl + (size_t)wave * 512 + (size_t)t * 4096),
        16, 0, 0);
  }
  __syncthreads();

  const float scale = 0.08838834764831843f;  // 1/sqrt(128)

  for (int half = 0; half < 2; ++half) {
    const int qb = half ? (15 - wave) : wave;
    const int q0 = qb * 16;

    bf16x8 qf[4];
#pragma unroll
    for (int dk = 0; dk < 4; ++dk)
      qf[dk] = *(const bf16x8*)(Qg + (size_t)(q0 + c) * N_HD + dk * 32 + g8 * 8);

    f32x4 o[8];
#pragma unroll
    for (int dj = 0; dj < 8; ++dj) o[dj] = (f32x4){0.f, 0.f, 0.f, 0.f};
    f32x4 mrow = (f32x4){-INFINITY, -INFINITY, -INFINITY, -INFINITY};
    f32x4 lrow = (f32x4){0.f, 0.f, 0.f, 0.f};

    const int nsteps = ((q0 + 15) >> 5) + 1;
    for (int js = 0; js < nsteps; ++js) {
      const int j0 = js * 32;

      // V fragments, first half (independent of QK -> latency hides under it)
      bf16x8 vf[4];
#pragma unroll
      for (int dj = 0; dj < 4; ++dj)
        vf[dj] = *(const bf16x8*)(Vg + (size_t)(dj * 16 + c) * N_L + j0 + g8 * 8);

      // ---- QK^T: S tile 16q x 32j ----
      f32x4 s0 = (f32x4){0.f, 0.f, 0.f, 0.f};
      f32x4 s1 = (f32x4){0.f, 0.f, 0.f, 0.f};
#pragma unroll
      for (int dk = 0; dk < 4; ++dk) {
        int row0 = j0 + c;
        int row1 = j0 + 16 + c;
        bf16x8 kf0 = *(const bf16x8*)(Kl + row0 * N_HD + (((dk * 4 + g8) ^ (row0 & 7)) << 3));
        bf16x8 kf1 = *(const bf16x8*)(Kl + row1 * N_HD + (((dk * 4 + g8) ^ (row1 & 7)) << 3));
        s0 = __builtin_amdgcn_mfma_f32_16x16x32_bf16(qf[dk], kf0, s0, 0, 0, 0);
        s1 = __builtin_amdgcn_mfma_f32_16x16x32_bf16(qf[dk], kf1, s1, 0, 0, 0);
      }

      // ---- scale + causal mask ----
      // Mask whenever the tile touches the upper triangle: j_max > q_min,
      // i.e. j0+31 > q0. (Round-2 bug: compared against q0+15, which left
      // the diagonal tile of every odd q-block unmasked.)
      f32x4 sv0, sv1;
#pragma unroll
      for (int r = 0; r < 4; ++r) { sv0[r] = s0[r] * scale; sv1[r] = s1[r] * scale; }
      if (j0 + 31 > q0) {
#pragma unroll
        for (int r = 0; r < 4; ++r) {
          int q = q0 + g8 * 4 + r;
          if (j0 + c > q)      sv0[r] = -INFINITY;
          if (j0 + 16 + c > q) sv1[r] = -INFINITY;
        }
      }

      // ---- online softmax (stats per q-row = per f32x4 component) ----
      f32x4 mx = max4(sv0, sv1);
      mx = max4(mx, shflx4(mx, 1));
      mx = max4(mx, shflx4(mx, 2));
      mx = max4(mx, shflx4(mx, 4));
      mx = max4(mx, shflx4(mx, 8));
      f32x4 mnew = max4(mrow, mx);
      f32x4 resc, p0, p1;
#pragma unroll
      for (int r = 0; r < 4; ++r) {
        resc[r] = __expf(mrow[r] - mnew[r]);
        p0[r] = __expf(sv0[r] - mnew[r]);
        p1[r] = __expf(sv1[r] - mnew[r]);
      }
      f32x4 rsum = p0 + p1;
      rsum += shflx4(rsum, 1);
      rsum += shflx4(rsum, 2);
      rsum += shflx4(rsum, 4);
      rsum += shflx4(rsum, 8);
      lrow = lrow * resc + rsum;
      mrow = mnew;
#pragma unroll
      for (int dj = 0; dj < 8; ++dj) o[dj] *= resc;

      // ---- P -> LDS (bf16), re-read as A-fragment ----
#pragma unroll
      for (int r = 0; r < 4; ++r) {
        Pl[wave][g8 * 4 + r][c] = (bf16)p0[r];
        Pl[wave][g8 * 4 + r][16 + c] = (bf16)p1[r];
      }
      bf16x8 pf = *(const bf16x8*)&Pl[wave][c][g8 * 8];

      // V fragments, second half
      bf16x8 vg[4];
#pragma unroll
      for (int dj = 0; dj < 4; ++dj)
        vg[dj] = *(const bf16x8*)(Vg + (size_t)((dj + 4) * 16 + c) * N_L + j0 + g8 * 8);

      // ---- PV ----
#pragma unroll
      for (int dj = 0; dj < 4; ++dj)
        o[dj] = __builtin_amdgcn_mfma_f32_16x16x32_bf16(pf, vf[dj], o[dj], 0, 0, 0);
#pragma unroll
      for (int dj = 0; dj < 4; ++dj)
        o[dj + 4] = __builtin_amdgcn_mfma_f32_16x16x32_bf16(pf, vg[dj], o[dj + 4], 0, 0, 0);
    }

    // ---- epilogue: normalize + write O[b][l][h][d] ----
    f32x4 inv;
#pragma unroll
    for (int r = 0; r < 4; ++r) inv[r] = 1.0f / lrow[r];
#pragma unroll
    for (int dj = 0; dj < 8; ++dj) {
      f32x4 ov = o[dj] * inv;
#pragma unroll
      for (int r = 0; r < 4; ++r) {
        int q = q0 + g8 * 4 + r;
        int d = dj * 16 + c;
        O[(((size_t)b * N_L + q) * N_H + h) * N_HD + d] = (bf16)ov[r];
      }
    }
  }
}

// ---------------- launch ----------------
extern "C" void kernel_launch(void* const* d_in, const int* in_sizes, int n_in,
                              void* d_out, int out_size, void* d_ws, size_t ws_size,
                              hipStream_t stream) {
  const float* x  = (const float*)d_in[0];
  const float* wq = (const float*)d_in[1];
  const float* bq = (const float*)d_in[2];
  const float* wk = (const float*)d_in[3];
  const float* bk = (const float*)d_in[4];
  const float* wv = (const float*)d_in[5];
  const float* bv = (const float*)d_in[6];
  const float* wo = (const float*)d_in[7];
  const float* bo = (const float*)d_in[8];

  char* ws = (char*)d_ws;
  const size_t WSZ = (size_t)N_D * N_D * sizeof(bf16);    // 8 MB per transposed weight
  const size_t XSZ = (size_t)M_TOT * N_D * sizeof(bf16);  // 64 MB per activation tensor
  bf16* wqT = (bf16*)(ws);
  bf16* wkT = (bf16*)(ws + WSZ);
  bf16* wvT = (bf16*)(ws + 2 * WSZ);
  bf16* woT = (bf16*)(ws + 3 * WSZ);
  bf16* xb  = (bf16*)(ws + 4 * WSZ);
  bf16* Qb  = (bf16*)(ws + 4 * WSZ + XSZ);
  bf16* Kb  = (bf16*)(ws + 4 * WSZ + 2 * XSZ);
  bf16* Vb  = (bf16*)(ws + 4 * WSZ + 3 * XSZ);  // holds V^T: [b][h][d][l]
  bf16* Ob  = (bf16*)(ws + 4 * WSZ + 4 * XSZ);
  float2* tab = (float2*)(ws + 4 * WSZ + 5 * XSZ);

  k_cast_x<<<2048, 256, 0, stream>>>(x, xb, M_TOT * N_D / 4);
  dim3 tb(32, 32), tg(64, 64);
  k_transpose_w<<<tg, tb, 0, stream>>>(wq, wqT);
  k_transpose_w<<<tg, tb, 0, stream>>>(wk, wkT);
  k_transpose_w<<<tg, tb, 0, stream>>>(wv, wvT);
  k_transpose_w<<<tg, tb, 0, stream>>>(wo, woT);
  k_trig<<<64, 256, 0, stream>>>(tab);

  dim3 gg(128, 16);
  k_gemm<0><<<gg, 256, 0, stream>>>(xb, wqT, bq, Qb);
  k_gemm<0><<<gg, 256, 0, stream>>>(xb, wkT, bk, Kb);
  k_gemm<2><<<gg, 256, 0, stream>>>(xb, wvT, bv, Vb);

  k_rope<<<4096, 256, 0, stream>>>(Qb, Kb, tab);
  k_attn_mfma<<<1024, 512, 0, stream>>>(Qb, Kb, Vb, Ob);
  k_gemm<1><<<gg, 256, 0, stream>>>(Ob, woT, bo, d_out);
}

// Round 4
// 906.001 us; speedup vs baseline: 4.1475x; 2.4013x over previous
//
#include <hip/hip_runtime.h>
#include <math.h>

typedef __bf16 bf16;
typedef float f32x4 __attribute__((ext_vector_type(4)));
typedef bf16  bf16x4 __attribute__((ext_vector_type(4)));
typedef bf16  bf16x8 __attribute__((ext_vector_type(8)));

#define N_B  64
#define N_L  256
#define N_H  16
#define N_D  2048
#define N_HD 128
#define M_TOT (N_B * N_L)   // 16384

static __device__ __forceinline__ float bfbits_lo(unsigned u) {
  union { unsigned u; float f; } c; c.u = u << 16; return c.f;
}
static __device__ __forceinline__ float bfbits_hi(unsigned u) {
  union { unsigned u; float f; } c; c.u = u & 0xffff0000u; return c.f;
}

static __device__ __forceinline__ f32x4 shflx4(f32x4 v, int m) {
  f32x4 r;
  r[0] = __shfl_xor(v[0], m);
  r[1] = __shfl_xor(v[1], m);
  r[2] = __shfl_xor(v[2], m);
  r[3] = __shfl_xor(v[3], m);
  return r;
}
static __device__ __forceinline__ f32x4 max4(f32x4 a, f32x4 b) {
  f32x4 r;
  r[0] = fmaxf(a[0], b[0]); r[1] = fmaxf(a[1], b[1]);
  r[2] = fmaxf(a[2], b[2]); r[3] = fmaxf(a[3], b[3]);
  return r;
}

// ---------------- prep kernels ----------------
__global__ void k_cast_x(const float* __restrict__ x, bf16* __restrict__ xb, int n4) {
  int i = blockIdx.x * blockDim.x + threadIdx.x;
  int st = gridDim.x * blockDim.x;
  for (; i < n4; i += st) {
    float4 v = ((const float4*)x)[i];
    bf16x4 o;
    o[0] = (bf16)v.x; o[1] = (bf16)v.y; o[2] = (bf16)v.z; o[3] = (bf16)v.w;
    ((bf16x4*)xb)[i] = o;
  }
}

__global__ void k_transpose_w(const float* __restrict__ w, bf16* __restrict__ wt) {
  __shared__ float t[32][33];
  int n0 = blockIdx.x * 32, k0 = blockIdx.y * 32;
  t[threadIdx.y][threadIdx.x] = w[(size_t)(k0 + threadIdx.y) * N_D + n0 + threadIdx.x];
  __syncthreads();
  wt[(size_t)(n0 + threadIdx.y) * N_D + k0 + threadIdx.x] = (bf16)t[threadIdx.x][threadIdx.y];
}

__global__ void k_trig(float2* __restrict__ tab) {
  int idx = blockIdx.x * blockDim.x + threadIdx.x;
  if (idx < N_L * (N_HD / 2)) {
    int l = idx >> 6, i = idx & 63;
    float ang = (float)l * powf(10000.0f, -(float)(2 * i) / 128.0f);
    tab[idx].x = cosf(ang);
    tab[idx].y = sinf(ang);
  }
}

// ---------------- MFMA GEMM: C[m][n] = sum_k A[m][k] * BT[n][k] + bias[n] ----------------
// BK=64, As/Bs [128][64] with XOR granule swizzle (granule ^= row&7), staged via
// global_load_lds(16B) with pre-swizzled per-lane global source (linear LDS dest).
// MODE 0: bf16 to [b][h][l][d] (unused now).  MODE 1: fp32 row-major (final out).
// MODE 2: bf16 to [b][h][d][l] (V transposed). MODE 3: MODE 0 + fused RoPE (Q,K).
template<int MODE>
__global__ __launch_bounds__(256) void k_gemm(
    const bf16* __restrict__ A, const bf16* __restrict__ BT,
    const float* __restrict__ bias, void* __restrict__ dstv,
    const float2* __restrict__ tab)
{
  __shared__ bf16 As[128][64];
  __shared__ bf16 Bs[128][64];
  const int m0 = blockIdx.x * 128;
  const int n0 = blockIdx.y * 128;
  const int tid = threadIdx.x;
  const int wave = tid >> 6, lane = tid & 63;
  const int wr = wave >> 1, wc = wave & 1;
  const int lr = lane & 15, lg = lane >> 4;
  const int srow = lane >> 3;          // row within 8-row staging chunk
  const int sg = lane & 7;             // LDS granule this lane fills

  f32x4 acc[4][4];
#pragma unroll
  for (int i = 0; i < 4; ++i)
#pragma unroll
    for (int j = 0; j < 4; ++j)
      acc[i][j] = (f32x4){0.f, 0.f, 0.f, 0.f};

  for (int k0 = 0; k0 < N_D; k0 += 64) {
    // stage 128x64 A and B tiles: 16 insts each, 4 per wave per matrix
#pragma unroll
    for (int t = 0; t < 4; ++t) {
      const int chunk = wave * 4 + t;            // 0..15, 8 rows each
      const int row = chunk * 8 + srow;
      const int goff = ((sg ^ (row & 7)) << 3);  // swizzled source granule
      const bf16* gA = A + (size_t)(m0 + row) * N_D + k0 + goff;
      __builtin_amdgcn_global_load_lds(
          (const __attribute__((address_space(1))) void*)gA,
          (__attribute__((address_space(3))) void*)&As[chunk * 8][0], 16, 0, 0);
      const bf16* gB = BT + (size_t)(n0 + row) * N_D + k0 + goff;
      __builtin_amdgcn_global_load_lds(
          (const __attribute__((address_space(1))) void*)gB,
          (__attribute__((address_space(3))) void*)&Bs[chunk * 8][0], 16, 0, 0);
    }
    __syncthreads();
#pragma unroll
    for (int kk = 0; kk < 2; ++kk) {
      bf16x8 af[4], bfr[4];
#pragma unroll
      for (int i = 0; i < 4; ++i) {
        const int ra = wr * 64 + i * 16 + lr;
        af[i] = *(const bf16x8*)&As[ra][((kk * 4 + lg) ^ (ra & 7)) << 3];
        const int rb = wc * 64 + i * 16 + lr;
        bfr[i] = *(const bf16x8*)&Bs[rb][((kk * 4 + lg) ^ (rb & 7)) << 3];
      }
#pragma unroll
      for (int i = 0; i < 4; ++i)
#pragma unroll
        for (int j = 0; j < 4; ++j)
          acc[i][j] = __builtin_amdgcn_mfma_f32_16x16x32_bf16(af[i], bfr[j], acc[i][j], 0, 0, 0);
    }
    __syncthreads();
  }

#pragma unroll
  for (int i = 0; i < 4; ++i) {
#pragma unroll
    for (int r = 0; r < 4; ++r) {
      const int m = m0 + wr * 64 + i * 16 + lg * 4 + r;
#pragma unroll
      for (int j = 0; j < 4; ++j) {
        const int n = n0 + wc * 64 + j * 16 + lr;
        float v = acc[i][j][r] + bias[n];
        if (MODE == 3) {
          // fused RoPE: lanes lr, lr^1 hold adjacent d at the same row m
          float partner = __shfl_xor(v, 1);
          const int d = n & 127, l = m & 255;
          float2 cs = tab[(l << 6) | (d >> 1)];
          v = (d & 1) ? (v * cs.x + partner * cs.y) : (v * cs.x - partner * cs.y);
        }
        if (MODE == 0 || MODE == 3) {
          bf16* dst = (bf16*)dstv;
          const int b = m >> 8, l = m & 255;
          const int h = n >> 7, d = n & 127;
          dst[(((size_t)b * N_H + h) * N_L + l) * N_HD + d] = (bf16)v;
        } else if (MODE == 2) {
          bf16* dst = (bf16*)dstv;
          const int b = m >> 8, l = m & 255;
          const int h = n >> 7, d = n & 127;
          dst[(((size_t)b * N_H + h) * N_HD + d) * N_L + l] = (bf16)v;
        } else {
          float* dst = (float*)dstv;
          dst[(size_t)m * N_D + n] = v;
        }
      }
    }
  }
}

// ---------------- MFMA flash attention: one block per (b,h), 8 waves ----------------
// Q,K in [b][h][l][d] (RoPE applied). Vt in [b][h][d][l]. O to [b][l][h][d].
__global__ __launch_bounds__(512) void k_attn_mfma(
    const bf16* __restrict__ Q, const bf16* __restrict__ K,
    const bf16* __restrict__ Vt, bf16* __restrict__ O)
{
  __shared__ bf16 Kl[N_L * N_HD];   // 64KB; row j = 256B = 16 granules; granule g holds src granule g^(j&7)
  __shared__ bf16 Pl[8][16][56];    // per-wave P staging; 112B row stride

  const int bh = blockIdx.x;
  const int b = bh >> 4, h = bh & 15;
  const int tid = threadIdx.x;
  const int wave = tid >> 6, lane = tid & 63;
  const int c = lane & 15, g8 = lane >> 4;

  const bf16* Qg = Q + (size_t)bh * (N_L * N_HD);
  const bf16* Kg = K + (size_t)bh * (N_L * N_HD);
  const bf16* Vg = Vt + (size_t)bh * (N_L * N_HD);

#pragma unroll
  for (int t = 0; t < 8; ++t) {
    int idx = tid + 512 * t;            // 16B-granule index, 4096 total
    int row = idx >> 4, g = idx & 15;
    const bf16* src = Kg + row * N_HD + ((g ^ (row & 7)) << 3);
    __builtin_amdgcn_global_load_lds(
        (const __attribute__((address_space(1))) void*)src,
        (__attribute__((address_space(3))) void*)(Kl + (size_t)wave * 512 + (size_t)t * 4096),
        16, 0, 0);
  }
  __syncthreads();

  const float scale = 0.08838834764831843f;  // 1/sqrt(128)

  for (int half = 0; half < 2; ++half) {
    const int qb = half ? (15 - wave) : wave;
    const int q0 = qb * 16;

    bf16x8 qf[4];
#pragma unroll
    for (int dk = 0; dk < 4; ++dk)
      qf[dk] = *(const bf16x8*)(Qg + (size_t)(q0 + c) * N_HD + dk * 32 + g8 * 8);

    f32x4 o[8];
#pragma unroll
    for (int dj = 0; dj < 8; ++dj) o[dj] = (f32x4){0.f, 0.f, 0.f, 0.f};
    f32x4 mrow = (f32x4){-INFINITY, -INFINITY, -INFINITY, -INFINITY};
    f32x4 lrow = (f32x4){0.f, 0.f, 0.f, 0.f};

    const int nsteps = ((q0 + 15) >> 5) + 1;
    for (int js = 0; js < nsteps; ++js) {
      const int j0 = js * 32;

      bf16x8 vf[4];
#pragma unroll
      for (int dj = 0; dj < 4; ++dj)
        vf[dj] = *(const bf16x8*)(Vg + (size_t)(dj * 16 + c) * N_L + j0 + g8 * 8);

      f32x4 s0 = (f32x4){0.f, 0.f, 0.f, 0.f};
      f32x4 s1 = (f32x4){0.f, 0.f, 0.f, 0.f};
#pragma unroll
      for (int dk = 0; dk < 4; ++dk) {
        int row0 = j0 + c;
        int row1 = j0 + 16 + c;
        bf16x8 kf0 = *(const bf16x8*)(Kl + row0 * N_HD + (((dk * 4 + g8) ^ (row0 & 7)) << 3));
        bf16x8 kf1 = *(const bf16x8*)(Kl + row1 * N_HD + (((dk * 4 + g8) ^ (row1 & 7)) << 3));
        s0 = __builtin_amdgcn_mfma_f32_16x16x32_bf16(qf[dk], kf0, s0, 0, 0, 0);
        s1 = __builtin_amdgcn_mfma_f32_16x16x32_bf16(qf[dk], kf1, s1, 0, 0, 0);
      }

      // mask whenever the tile touches the upper triangle: j0+31 > q0
      f32x4 sv0, sv1;
#pragma unroll
      for (int r = 0; r < 4; ++r) { sv0[r] = s0[r] * scale; sv1[r] = s1[r] * scale; }
      if (j0 + 31 > q0) {
#pragma unroll
        for (int r = 0; r < 4; ++r) {
          int q = q0 + g8 * 4 + r;
          if (j0 + c > q)      sv0[r] = -INFINITY;
          if (j0 + 16 + c > q) sv1[r] = -INFINITY;
        }
      }

      f32x4 mx = max4(sv0, sv1);
      mx = max4(mx, shflx4(mx, 1));
      mx = max4(mx, shflx4(mx, 2));
      mx = max4(mx, shflx4(mx, 4));
      mx = max4(mx, shflx4(mx, 8));
      f32x4 mnew = max4(mrow, mx);
      f32x4 resc, p0, p1;
#pragma unroll
      for (int r = 0; r < 4; ++r) {
        resc[r] = __expf(mrow[r] - mnew[r]);
        p0[r] = __expf(sv0[r] - mnew[r]);
        p1[r] = __expf(sv1[r] - mnew[r]);
      }
      f32x4 rsum = p0 + p1;
      rsum += shflx4(rsum, 1);
      rsum += shflx4(rsum, 2);
      rsum += shflx4(rsum, 4);
      rsum += shflx4(rsum, 8);
      lrow = lrow * resc + rsum;
      mrow = mnew;
#pragma unroll
      for (int dj = 0; dj < 8; ++dj) o[dj] *= resc;

#pragma unroll
      for (int r = 0; r < 4; ++r) {
        Pl[wave][g8 * 4 + r][c] = (bf16)p0[r];
        Pl[wave][g8 * 4 + r][16 + c] = (bf16)p1[r];
      }
      bf16x8 pf = *(const bf16x8*)&Pl[wave][c][g8 * 8];

      bf16x8 vg[4];
#pragma unroll
      for (int dj = 0; dj < 4; ++dj)
        vg[dj] = *(const bf16x8*)(Vg + (size_t)((dj + 4) * 16 + c) * N_L + j0 + g8 * 8);

#pragma unroll
      for (int dj = 0; dj < 4; ++dj)
        o[dj] = __builtin_amdgcn_mfma_f32_16x16x32_bf16(pf, vf[dj], o[dj], 0, 0, 0);
#pragma unroll
      for (int dj = 0; dj < 4; ++dj)
        o[dj + 4] = __builtin_amdgcn_mfma_f32_16x16x32_bf16(pf, vg[dj], o[dj + 4], 0, 0, 0);
    }

    f32x4 inv;
#pragma unroll
    for (int r = 0; r < 4; ++r) inv[r] = 1.0f / lrow[r];
#pragma unroll
    for (int dj = 0; dj < 8; ++dj) {
      f32x4 ov = o[dj] * inv;
#pragma unroll
      for (int r = 0; r < 4; ++r) {
        int q = q0 + g8 * 4 + r;
        int d = dj * 16 + c;
        O[(((size_t)b * N_L + q) * N_H + h) * N_HD + d] = (bf16)ov[r];
      }
    }
  }
}

// ---------------- launch ----------------
extern "C" void kernel_launch(void* const* d_in, const int* in_sizes, int n_in,
                              void* d_out, int out_size, void* d_ws, size_t ws_size,
                              hipStream_t stream) {
  const float* x  = (const float*)d_in[0];
  const float* wq = (const float*)d_in[1];
  const float* bq = (const float*)d_in[2];
  const float* wk = (const float*)d_in[3];
  const float* bk = (const float*)d_in[4];
  const float* wv = (const float*)d_in[5];
  const float* bv = (const float*)d_in[6];
  const float* wo = (const float*)d_in[7];
  const float* bo = (const float*)d_in[8];

  char* ws = (char*)d_ws;
  const size_t WSZ = (size_t)N_D * N_D * sizeof(bf16);    // 8 MB per transposed weight
  const size_t XSZ = (size_t)M_TOT * N_D * sizeof(bf16);  // 64 MB per activation tensor
  bf16* wqT = (bf16*)(ws);
  bf16* wkT = (bf16*)(ws + WSZ);
  bf16* wvT = (bf16*)(ws + 2 * WSZ);
  bf16* woT = (bf16*)(ws + 3 * WSZ);
  bf16* xb  = (bf16*)(ws + 4 * WSZ);
  bf16* Qb  = (bf16*)(ws + 4 * WSZ + XSZ);
  bf16* Kb  = (bf16*)(ws + 4 * WSZ + 2 * XSZ);
  bf16* Vb  = (bf16*)(ws + 4 * WSZ + 3 * XSZ);  // holds V^T: [b][h][d][l]
  bf16* Ob  = (bf16*)(ws + 4 * WSZ + 4 * XSZ);
  float2* tab = (float2*)(ws + 4 * WSZ + 5 * XSZ);

  k_cast_x<<<2048, 256, 0, stream>>>(x, xb, M_TOT * N_D / 4);
  dim3 tb(32, 32), tg(64, 64);
  k_transpose_w<<<tg, tb, 0, stream>>>(wq, wqT);
  k_transpose_w<<<tg, tb, 0, stream>>>(wk, wkT);
  k_transpose_w<<<tg, tb, 0, stream>>>(wv, wvT);
  k_transpose_w<<<tg, tb, 0, stream>>>(wo, woT);
  k_trig<<<64, 256, 0, stream>>>(tab);

  dim3 gg(128, 16);
  k_gemm<3><<<gg, 256, 0, stream>>>(xb, wqT, bq, Qb, tab);   // Q proj + RoPE
  k_gemm<3><<<gg, 256, 0, stream>>>(xb, wkT, bk, Kb, tab);   // K proj + RoPE
  k_gemm<2><<<gg, 256, 0, stream>>>(xb, wvT, bv, Vb, tab);   // V proj, transposed

  k_attn_mfma<<<1024, 512, 0, stream>>>(Qb, Kb, Vb, Ob);
  k_gemm<1><<<gg, 256, 0, stream>>>(Ob, woT, bo, d_out, tab);
}

// Round 5
// 700.312 us; speedup vs baseline: 5.3657x; 1.2937x over previous
//
#include <hip/hip_runtime.h>
#include <math.h>

typedef __bf16 bf16;
typedef float f32x4 __attribute__((ext_vector_type(4)));
typedef bf16  bf16x4 __attribute__((ext_vector_type(4)));
typedef bf16  bf16x8 __attribute__((ext_vector_type(8)));

#define N_B  64
#define N_L  256
#define N_H  16
#define N_D  2048
#define N_HD 128
#define M_TOT (N_B * N_L)   // 16384

static __device__ __forceinline__ float bfbits_lo(unsigned u) {
  union { unsigned u; float f; } c; c.u = u << 16; return c.f;
}
static __device__ __forceinline__ float bfbits_hi(unsigned u) {
  union { unsigned u; float f; } c; c.u = u & 0xffff0000u; return c.f;
}

static __device__ __forceinline__ f32x4 shflx4(f32x4 v, int m) {
  f32x4 r;
  r[0] = __shfl_xor(v[0], m);
  r[1] = __shfl_xor(v[1], m);
  r[2] = __shfl_xor(v[2], m);
  r[3] = __shfl_xor(v[3], m);
  return r;
}
static __device__ __forceinline__ f32x4 max4(f32x4 a, f32x4 b) {
  f32x4 r;
  r[0] = fmaxf(a[0], b[0]); r[1] = fmaxf(a[1], b[1]);
  r[2] = fmaxf(a[2], b[2]); r[3] = fmaxf(a[3], b[3]);
  return r;
}

// ---------------- prep kernels ----------------
__global__ void k_cast_x(const float* __restrict__ x, bf16* __restrict__ xb, int n4) {
  int i = blockIdx.x * blockDim.x + threadIdx.x;
  int st = gridDim.x * blockDim.x;
  for (; i < n4; i += st) {
    float4 v = ((const float4*)x)[i];
    bf16x4 o;
    o[0] = (bf16)v.x; o[1] = (bf16)v.y; o[2] = (bf16)v.z; o[3] = (bf16)v.w;
    ((bf16x4*)xb)[i] = o;
  }
}

__global__ void k_transpose_w(const float* __restrict__ w, bf16* __restrict__ wt) {
  __shared__ float t[32][33];
  int n0 = blockIdx.x * 32, k0 = blockIdx.y * 32;
  t[threadIdx.y][threadIdx.x] = w[(size_t)(k0 + threadIdx.y) * N_D + n0 + threadIdx.x];
  __syncthreads();
  wt[(size_t)(n0 + threadIdx.y) * N_D + k0 + threadIdx.x] = (bf16)t[threadIdx.x][threadIdx.y];
}

__global__ void k_trig(float2* __restrict__ tab) {
  int idx = blockIdx.x * blockDim.x + threadIdx.x;
  if (idx < N_L * (N_HD / 2)) {
    int l = idx >> 6, i = idx & 63;
    float ang = (float)l * powf(10000.0f, -(float)(2 * i) / 128.0f);
    tab[idx].x = cosf(ang);
    tab[idx].y = sinf(ang);
  }
}

// ---------------- 256x256 8-phase MFMA GEMM ----------------
// C[m][n] = sum_k A[m][k] * BT[n][k] + bias[n]
// 8 waves (2M x 4N), per-wave 128x64 output, BK=64, double-buffered 128KB LDS.
// Counted vmcnt (never 0 in loop), raw s_barrier, setprio around MFMA clusters.
// MODE 1: fp32 row-major.  MODE 2: bf16 [b][h][d][l] (V^T).  MODE 3: bf16 [b][h][l][d] + RoPE.

#define GLOAD(GP, LP) __builtin_amdgcn_global_load_lds( \
    (const __attribute__((address_space(1))) void*)(GP), \
    (__attribute__((address_space(3))) void*)(LP), 16, 0, 0)
#define BARR()  __builtin_amdgcn_s_barrier()
#define SCHED() __builtin_amdgcn_sched_barrier(0)
#define PRIO1() __builtin_amdgcn_s_setprio(1)
#define PRIO0() __builtin_amdgcn_s_setprio(0)
#define WAITLGKM() asm volatile("s_waitcnt lgkmcnt(0)" ::: "memory")
#define WAITVM8()  asm volatile("s_waitcnt vmcnt(8)" ::: "memory")

#define STAGE_A(X, KT, BUF) do { \
  GLOAD(Ag + (size_t)srcOffA[0][X] + (size_t)(KT) * 64, (BUF) + ldsOffA[0][X]); \
  GLOAD(Ag + (size_t)srcOffA[1][X] + (size_t)(KT) * 64, (BUF) + ldsOffA[1][X]); \
} while (0)
#define STAGE_B(X, KT, BUF) do { \
  GLOAD(Bg + (size_t)srcOffB[0][X] + (size_t)(KT) * 64, (BUF) + ldsOffB[0][X]); \
  GLOAD(Bg + (size_t)srcOffB[1][X] + (size_t)(KT) * 64, (BUF) + ldsOffB[1][X]); \
} while (0)

#define LDA(QM, BUF) do { \
  _Pragma("unroll") for (int i_ = 0; i_ < 4; ++i_) { \
    const int R_ = wm * 128 + ((QM) * 4 + i_) * 16 + lr; \
    _Pragma("unroll") for (int kk_ = 0; kk_ < 2; ++kk_) \
      afr[i_][kk_] = *(const bf16x8*)&(BUF)[R_ * 64 + (((kk_ * 4 + lg) ^ (R_ & 7)) << 3)]; \
  } \
} while (0)
#define LDB(DST, QN, BUF) do { \
  _Pragma("unroll") for (int j_ = 0; j_ < 2; ++j_) { \
    const int R_ = wn * 64 + ((QN) * 2 + j_) * 16 + lr; \
    _Pragma("unroll") for (int kk_ = 0; kk_ < 2; ++kk_) \
      DST[j_][kk_] = *(const bf16x8*)&(BUF)[R_ * 64 + (((kk_ * 4 + lg) ^ (R_ & 7)) << 3)]; \
  } \
} while (0)

#define MFMA16(BF, QM, QN) do { \
  _Pragma("unroll") for (int i_ = 0; i_ < 4; ++i_) \
  _Pragma("unroll") for (int j_ = 0; j_ < 2; ++j_) \
  _Pragma("unroll") for (int kk_ = 0; kk_ < 2; ++kk_) \
    acc[(QM) * 4 + i_][(QN) * 2 + j_] = __builtin_amdgcn_mfma_f32_16x16x32_bf16( \
        afr[i_][kk_], BF[j_][kk_], acc[(QM) * 4 + i_][(QN) * 2 + j_], 0, 0, 0); \
} while (0)

// One K-tile = 4 phases (quadrants). Stage schedule (ledger-verified):
//   g0: stage B1(T+1)->OTH   g1: stage A1(T+1)->OTH
//   g2: stage A0(T+2)->CUR   g3: stage B0(T+2)->CUR
// vmcnt(8) at end of g0,g1,g3 drains exactly the half needed by the next phase.
#define TILE(T, CURA, CURB, OTHA, OTHB) do { \
  /* g0 */ \
  LDA(0, CURA); LDB(bfr0, 0, CURB); STAGE_B(1, (T) + 1, OTHB); \
  SCHED(); BARR(); WAITLGKM(); SCHED(); \
  PRIO1(); MFMA16(bfr0, 0, 0); PRIO0(); \
  SCHED(); WAITVM8(); BARR(); SCHED(); \
  /* g1 */ \
  LDB(bfr1, 1, CURB); STAGE_A(1, (T) + 1, OTHA); \
  SCHED(); BARR(); WAITLGKM(); SCHED(); \
  PRIO1(); MFMA16(bfr1, 0, 1); PRIO0(); \
  SCHED(); WAITVM8(); BARR(); SCHED(); \
  /* g2 */ \
  LDA(1, CURA); STAGE_A(0, (T) + 2, CURA); \
  SCHED(); BARR(); WAITLGKM(); SCHED(); \
  PRIO1(); MFMA16(bfr0, 1, 0); PRIO0(); \
  SCHED(); BARR(); SCHED(); \
  /* g3 */ \
  STAGE_B(0, (T) + 2, CURB); \
  SCHED(); BARR(); SCHED(); \
  PRIO1(); MFMA16(bfr1, 1, 1); PRIO0(); \
  SCHED(); WAITVM8(); BARR(); SCHED(); \
} while (0)

template<int MODE>
__global__ __launch_bounds__(512, 2) void k_gemm256(
    const bf16* __restrict__ A, const bf16* __restrict__ BT,
    const float* __restrict__ bias, void* __restrict__ dstv,
    const float2* __restrict__ tab)
{
  __shared__ bf16 lds[2][2][256 * 64];   // [buf][A=0/B=1], 128 KB total
  const int bid = blockIdx.x;
  const int bm = bid >> 3, bn = bid & 7;   // XCD swizzle: bn = bid%8 -> one n-panel per XCD
  const int m0 = bm * 256, n0 = bn * 256;
  const int tid = threadIdx.x;
  const int wave = tid >> 6, lane = tid & 63;
  const int wm = wave >> 2, wn = wave & 3;
  const int lr = lane & 15, lg = lane >> 4;
  const bf16* __restrict__ Ag = A;
  const bf16* __restrict__ Bg = BT;

  // staging address precompute (per-thread; element offsets fit int32)
  int srcOffA[2][2], srcOffB[2][2], ldsOffA[2][2], ldsOffB[2][2];
  {
    const int g7 = tid & 7;
#pragma unroll
    for (int u = 0; u < 2; ++u) {
      const int rl  = u * 64 + (tid >> 3);
      const int rl0 = u * 64 + wave * 8;
#pragma unroll
      for (int X = 0; X < 2; ++X) {
        const int rA  = ((rl >> 6) << 7)  | (X << 6) | (rl & 63);
        const int rA0 = ((rl0 >> 6) << 7) | (X << 6) | (rl0 & 63);
        srcOffA[u][X] = (m0 + rA) * N_D + ((g7 ^ (rA & 7)) << 3);
        ldsOffA[u][X] = rA0 * 64;
        const int rB  = ((rl >> 5) << 6)  | (X << 5) | (rl & 31);
        const int rB0 = ((rl0 >> 5) << 6) | (X << 5) | (rl0 & 31);
        srcOffB[u][X] = (n0 + rB) * N_D + ((g7 ^ (rB & 7)) << 3);
        ldsOffB[u][X] = rB0 * 64;
      }
    }
  }

  bf16* bufA0 = &lds[0][0][0];
  bf16* bufB0 = &lds[0][1][0];
  bf16* bufA1 = &lds[1][0][0];
  bf16* bufB1 = &lds[1][1][0];

  f32x4 acc[8][4];
#pragma unroll
  for (int i = 0; i < 8; ++i)
#pragma unroll
    for (int j = 0; j < 4; ++j)
      acc[i][j] = (f32x4){0.f, 0.f, 0.f, 0.f};

  bf16x8 afr[4][2], bfr0[2][2], bfr1[2][2];

  // prologue: tile0 fully + tile1 halves A0,B0  (12 loads); drain A0(0),B0(0)
  STAGE_A(0, 0, bufA0); STAGE_B(0, 0, bufB0);
  STAGE_B(1, 0, bufB0); STAGE_A(1, 0, bufA0);
  STAGE_A(0, 1, bufA1); STAGE_B(0, 1, bufB1);
  SCHED(); WAITVM8(); BARR(); SCHED();

#pragma unroll 1
  for (int t = 0; t < N_D / 64; t += 2) {
    TILE(t,     bufA0, bufB0, bufA1, bufB1);
    TILE(t + 1, bufA1, bufB1, bufA0, bufB0);
  }

  // ---- epilogue ----
#pragma unroll
  for (int i = 0; i < 8; ++i) {
#pragma unroll
    for (int r = 0; r < 4; ++r) {
      const int m = m0 + wm * 128 + i * 16 + lg * 4 + r;
#pragma unroll
      for (int j = 0; j < 4; ++j) {
        const int n = n0 + wn * 64 + j * 16 + lr;
        float v = acc[i][j][r] + bias[n];
        if (MODE == 3) {
          // fused RoPE: lanes lr, lr^1 hold adjacent d at the same row m
          float partner = __shfl_xor(v, 1);
          const int d = n & 127, l = m & 255;
          float2 cs = tab[(l << 6) | (d >> 1)];
          v = (d & 1) ? (v * cs.x + partner * cs.y) : (v * cs.x - partner * cs.y);
        }
        if (MODE == 0 || MODE == 3) {
          bf16* dst = (bf16*)dstv;
          const int b = m >> 8, l = m & 255;
          const int h = n >> 7, d = n & 127;
          dst[(((size_t)b * N_H + h) * N_L + l) * N_HD + d] = (bf16)v;
        } else if (MODE == 2) {
          bf16* dst = (bf16*)dstv;
          const int b = m >> 8, l = m & 255;
          const int h = n >> 7, d = n & 127;
          dst[(((size_t)b * N_H + h) * N_HD + d) * N_L + l] = (bf16)v;
        } else {
          float* dst = (float*)dstv;
          dst[(size_t)m * N_D + n] = v;
        }
      }
    }
  }
}

// ---------------- MFMA flash attention: one block per (b,h), 8 waves ----------------
// Q,K in [b][h][l][d] (RoPE applied). Vt in [b][h][d][l]. O to [b][l][h][d].
__global__ __launch_bounds__(512) void k_attn_mfma(
    const bf16* __restrict__ Q, const bf16* __restrict__ K,
    const bf16* __restrict__ Vt, bf16* __restrict__ O)
{
  __shared__ bf16 Kl[N_L * N_HD];   // 64KB; row j = 256B = 16 granules; granule g holds src granule g^(j&7)
  __shared__ bf16 Pl[8][16][56];    // per-wave P staging; 112B row stride

  const int bh = blockIdx.x;
  const int b = bh >> 4, h = bh & 15;
  const int tid = threadIdx.x;
  const int wave = tid >> 6, lane = tid & 63;
  const int c = lane & 15, g8 = lane >> 4;

  const bf16* Qg = Q + (size_t)bh * (N_L * N_HD);
  const bf16* Kg = K + (size_t)bh * (N_L * N_HD);
  const bf16* Vg = Vt + (size_t)bh * (N_L * N_HD);

#pragma unroll
  for (int t = 0; t < 8; ++t) {
    int idx = tid + 512 * t;            // 16B-granule index, 4096 total
    int row = idx >> 4, g = idx & 15;
    const bf16* src = Kg + row * N_HD + ((g ^ (row & 7)) << 3);
    __builtin_amdgcn_global_load_lds(
        (const __attribute__((address_space(1))) void*)src,
        (__attribute__((address_space(3))) void*)(Kl + (size_t)wave * 512 + (size_t)t * 4096),
        16, 0, 0);
  }
  __syncthreads();

  const float scale = 0.08838834764831843f;  // 1/sqrt(128)

  for (int half = 0; half < 2; ++half) {
    const int qb = half ? (15 - wave) : wave;
    const int q0 = qb * 16;

    bf16x8 qf[4];
#pragma unroll
    for (int dk = 0; dk < 4; ++dk)
      qf[dk] = *(const bf16x8*)(Qg + (size_t)(q0 + c) * N_HD + dk * 32 + g8 * 8);

    f32x4 o[8];
#pragma unroll
    for (int dj = 0; dj < 8; ++dj) o[dj] = (f32x4){0.f, 0.f, 0.f, 0.f};
    f32x4 mrow = (f32x4){-INFINITY, -INFINITY, -INFINITY, -INFINITY};
    f32x4 lrow = (f32x4){0.f, 0.f, 0.f, 0.f};

    const int nsteps = ((q0 + 15) >> 5) + 1;
    for (int js = 0; js < nsteps; ++js) {
      const int j0 = js * 32;

      bf16x8 vf[4];
#pragma unroll
      for (int dj = 0; dj < 4; ++dj)
        vf[dj] = *(const bf16x8*)(Vg + (size_t)(dj * 16 + c) * N_L + j0 + g8 * 8);

      f32x4 s0 = (f32x4){0.f, 0.f, 0.f, 0.f};
      f32x4 s1 = (f32x4){0.f, 0.f, 0.f, 0.f};
#pragma unroll
      for (int dk = 0; dk < 4; ++dk) {
        int row0 = j0 + c;
        int row1 = j0 + 16 + c;
        bf16x8 kf0 = *(const bf16x8*)(Kl + row0 * N_HD + (((dk * 4 + g8) ^ (row0 & 7)) << 3));
        bf16x8 kf1 = *(const bf16x8*)(Kl + row1 * N_HD + (((dk * 4 + g8) ^ (row1 & 7)) << 3));
        s0 = __builtin_amdgcn_mfma_f32_16x16x32_bf16(qf[dk], kf0, s0, 0, 0, 0);
        s1 = __builtin_amdgcn_mfma_f32_16x16x32_bf16(qf[dk], kf1, s1, 0, 0, 0);
      }

      // mask whenever the tile touches the upper triangle: j0+31 > q0
      f32x4 sv0, sv1;
#pragma unroll
      for (int r = 0; r < 4; ++r) { sv0[r] = s0[r] * scale; sv1[r] = s1[r] * scale; }
      if (j0 + 31 > q0) {
#pragma unroll
        for (int r = 0; r < 4; ++r) {
          int q = q0 + g8 * 4 + r;
          if (j0 + c > q)      sv0[r] = -INFINITY;
          if (j0 + 16 + c > q) sv1[r] = -INFINITY;
        }
      }

      f32x4 mx = max4(sv0, sv1);
      mx = max4(mx, shflx4(mx, 1));
      mx = max4(mx, shflx4(mx, 2));
      mx = max4(mx, shflx4(mx, 4));
      mx = max4(mx, shflx4(mx, 8));
      f32x4 mnew = max4(mrow, mx);
      f32x4 resc, p0, p1;
#pragma unroll
      for (int r = 0; r < 4; ++r) {
        resc[r] = __expf(mrow[r] - mnew[r]);
        p0[r] = __expf(sv0[r] - mnew[r]);
        p1[r] = __expf(sv1[r] - mnew[r]);
      }
      f32x4 rsum = p0 + p1;
      rsum += shflx4(rsum, 1);
      rsum += shflx4(rsum, 2);
      rsum += shflx4(rsum, 4);
      rsum += shflx4(rsum, 8);
      lrow = lrow * resc + rsum;
      mrow = mnew;
#pragma unroll
      for (int dj = 0; dj < 8; ++dj) o[dj] *= resc;

#pragma unroll
      for (int r = 0; r < 4; ++r) {
        Pl[wave][g8 * 4 + r][c] = (bf16)p0[r];
        Pl[wave][g8 * 4 + r][16 + c] = (bf16)p1[r];
      }
      bf16x8 pf = *(const bf16x8*)&Pl[wave][c][g8 * 8];

      bf16x8 vg[4];
#pragma unroll
      for (int dj = 0; dj < 4; ++dj)
        vg[dj] = *(const bf16x8*)(Vg + (size_t)((dj + 4) * 16 + c) * N_L + j0 + g8 * 8);

#pragma unroll
      for (int dj = 0; dj < 4; ++dj)
        o[dj] = __builtin_amdgcn_mfma_f32_16x16x32_bf16(pf, vf[dj], o[dj], 0, 0, 0);
#pragma unroll
      for (int dj = 0; dj < 4; ++dj)
        o[dj + 4] = __builtin_amdgcn_mfma_f32_16x16x32_bf16(pf, vg[dj], o[dj + 4], 0, 0, 0);
    }

    f32x4 inv;
#pragma unroll
    for (int r = 0; r < 4; ++r) inv[r] = 1.0f / lrow[r];
#pragma unroll
    for (int dj = 0; dj < 8; ++dj) {
      f32x4 ov = o[dj] * inv;
#pragma unroll
      for (int r = 0; r < 4; ++r) {
        int q = q0 + g8 * 4 + r;
        int d = dj * 16 + c;
        O[(((size_t)b * N_L + q) * N_H + h) * N_HD + d] = (bf16)ov[r];
      }
    }
  }
}

// ---------------- launch ----------------
extern "C" void kernel_launch(void* const* d_in, const int* in_sizes, int n_in,
                              void* d_out, int out_size, void* d_ws, size_t ws_size,
                              hipStream_t stream) {
  const float* x  = (const float*)d_in[0];
  const float* wq = (const float*)d_in[1];
  const float* bq = (const float*)d_in[2];
  const float* wk = (const float*)d_in[3];
  const float* bk = (const float*)d_in[4];
  const float* wv = (const float*)d_in[5];
  const float* bv = (const float*)d_in[6];
  const float* wo = (const float*)d_in[7];
  const float* bo = (const float*)d_in[8];

  char* ws = (char*)d_ws;
  const size_t WSZ = (size_t)N_D * N_D * sizeof(bf16);    // 8 MB per transposed weight
  const size_t XSZ = (size_t)M_TOT * N_D * sizeof(bf16);  // 64 MB per activation tensor
  bf16* wqT = (bf16*)(ws);
  bf16* wkT = (bf16*)(ws + WSZ);
  bf16* wvT = (bf16*)(ws + 2 * WSZ);
  bf16* woT = (bf16*)(ws + 3 * WSZ);
  bf16* xb  = (bf16*)(ws + 4 * WSZ);
  bf16* Qb  = (bf16*)(ws + 4 * WSZ + XSZ);
  bf16* Kb  = (bf16*)(ws + 4 * WSZ + 2 * XSZ);
  bf16* Vb  = (bf16*)(ws + 4 * WSZ + 3 * XSZ);  // holds V^T: [b][h][d][l]
  bf16* Ob  = (bf16*)(ws + 4 * WSZ + 4 * XSZ);
  float2* tab = (float2*)(ws + 4 * WSZ + 5 * XSZ);

  k_cast_x<<<2048, 256, 0, stream>>>(x, xb, M_TOT * N_D / 4);
  dim3 tb(32, 32), tg(64, 64);
  k_transpose_w<<<tg, tb, 0, stream>>>(wq, wqT);
  k_transpose_w<<<tg, tb, 0, stream>>>(wk, wkT);
  k_transpose_w<<<tg, tb, 0, stream>>>(wv, wvT);
  k_transpose_w<<<tg, tb, 0, stream>>>(wo, woT);
  k_trig<<<64, 256, 0, stream>>>(tab);

  const int grid = (M_TOT / 256) * (N_D / 256);  // 512
  k_gemm256<3><<<grid, 512, 0, stream>>>(xb, wqT, bq, Qb, tab);   // Q proj + RoPE
  k_gemm256<3><<<grid, 512, 0, stream>>>(xb, wkT, bk, Kb, tab);   // K proj + RoPE
  k_gemm256<2><<<grid, 512, 0, stream>>>(xb, wvT, bv, Vb, tab);   // V proj, transposed

  k_attn_mfma<<<1024, 512, 0, stream>>>(Qb, Kb, Vb, Ob);
  k_gemm256<1><<<grid, 512, 0, stream>>>(Ob, woT, bo, d_out, tab);
}

// Round 6
// 679.562 us; speedup vs baseline: 5.5296x; 1.0305x over previous
//
#include <hip/hip_runtime.h>
#include <math.h>

typedef __bf16 bf16;
typedef float f32x4 __attribute__((ext_vector_type(4)));
typedef bf16  bf16x4 __attribute__((ext_vector_type(4)));
typedef bf16  bf16x8 __attribute__((ext_vector_type(8)));

#define N_B  64
#define N_L  256
#define N_H  16
#define N_D  2048
#define N_HD 128
#define M_TOT (N_B * N_L)   // 16384

static __device__ __forceinline__ float bfbits_lo(unsigned u) {
  union { unsigned u; float f; } c; c.u = u << 16; return c.f;
}
static __device__ __forceinline__ float bfbits_hi(unsigned u) {
  union { unsigned u; float f; } c; c.u = u & 0xffff0000u; return c.f;
}

static __device__ __forceinline__ f32x4 shflx4(f32x4 v, int m) {
  f32x4 r;
  r[0] = __shfl_xor(v[0], m);
  r[1] = __shfl_xor(v[1], m);
  r[2] = __shfl_xor(v[2], m);
  r[3] = __shfl_xor(v[3], m);
  return r;
}
static __device__ __forceinline__ f32x4 max4(f32x4 a, f32x4 b) {
  f32x4 r;
  r[0] = fmaxf(a[0], b[0]); r[1] = fmaxf(a[1], b[1]);
  r[2] = fmaxf(a[2], b[2]); r[3] = fmaxf(a[3], b[3]);
  return r;
}

// ---------------- prep kernels ----------------
__global__ void k_cast_x(const float* __restrict__ x, bf16* __restrict__ xb, int n4) {
  int i = blockIdx.x * blockDim.x + threadIdx.x;
  int st = gridDim.x * blockDim.x;
  for (; i < n4; i += st) {
    float4 v = ((const float4*)x)[i];
    bf16x4 o;
    o[0] = (bf16)v.x; o[1] = (bf16)v.y; o[2] = (bf16)v.z; o[3] = (bf16)v.w;
    ((bf16x4*)xb)[i] = o;
  }
}

__global__ void k_transpose_w(const float* __restrict__ w, bf16* __restrict__ wt) {
  __shared__ float t[32][33];
  int n0 = blockIdx.x * 32, k0 = blockIdx.y * 32;
  t[threadIdx.y][threadIdx.x] = w[(size_t)(k0 + threadIdx.y) * N_D + n0 + threadIdx.x];
  __syncthreads();
  wt[(size_t)(n0 + threadIdx.y) * N_D + k0 + threadIdx.x] = (bf16)t[threadIdx.x][threadIdx.y];
}

__global__ void k_trig(float2* __restrict__ tab) {
  int idx = blockIdx.x * blockDim.x + threadIdx.x;
  if (idx < N_L * (N_HD / 2)) {
    int l = idx >> 6, i = idx & 63;
    float ang = (float)l * powf(10000.0f, -(float)(2 * i) / 128.0f);
    tab[idx].x = cosf(ang);
    tab[idx].y = sinf(ang);
  }
}

// ---------------- 256x256 8-phase MFMA GEMM ----------------
// C[m][n] = sum_k A[m][k] * BT[n][k] + bias[n]
// 8 waves (2M x 4N), per-wave 128x64 output, BK=64, double-buffered 128KB LDS.
// ONE counted vmcnt(4) per K-tile (ledger-verified), raw s_barrier, setprio.
// MODE 1: fp32 row-major.  MODE 2: bf16 [b][h][d][l] (V^T).  MODE 3: bf16 [b][h][l][d] + RoPE.

#define GLOAD(GP, LP) __builtin_amdgcn_global_load_lds( \
    (const __attribute__((address_space(1))) void*)(GP), \
    (__attribute__((address_space(3))) void*)(LP), 16, 0, 0)
#define BARR()  __builtin_amdgcn_s_barrier()
#define SCHED() __builtin_amdgcn_sched_barrier(0)
#define PRIO1() __builtin_amdgcn_s_setprio(1)
#define PRIO0() __builtin_amdgcn_s_setprio(0)
#define WAITLGKM() asm volatile("s_waitcnt lgkmcnt(0)" ::: "memory")
#define WAITVM4()  asm volatile("s_waitcnt vmcnt(4)" ::: "memory")

// KT masked &31 so the two tail tiles stage in-range (never-read) garbage.
#define STAGE_A(X, KT, BUF) do { \
  GLOAD(Ag + (size_t)srcOffA[0][X] + (size_t)((KT) & 31) * 64, (BUF) + ldsOffA[0][X]); \
  GLOAD(Ag + (size_t)srcOffA[1][X] + (size_t)((KT) & 31) * 64, (BUF) + ldsOffA[1][X]); \
} while (0)
#define STAGE_B(X, KT, BUF) do { \
  GLOAD(Bg + (size_t)srcOffB[0][X] + (size_t)((KT) & 31) * 64, (BUF) + ldsOffB[0][X]); \
  GLOAD(Bg + (size_t)srcOffB[1][X] + (size_t)((KT) & 31) * 64, (BUF) + ldsOffB[1][X]); \
} while (0)

#define LDA(QM, BUF) do { \
  _Pragma("unroll") for (int i_ = 0; i_ < 4; ++i_) { \
    const int R_ = wm * 128 + ((QM) * 4 + i_) * 16 + lr; \
    _Pragma("unroll") for (int kk_ = 0; kk_ < 2; ++kk_) \
      afr[i_][kk_] = *(const bf16x8*)&(BUF)[R_ * 64 + (((kk_ * 4 + lg) ^ (R_ & 7)) << 3)]; \
  } \
} while (0)
#define LDB(DST, QN, BUF) do { \
  _Pragma("unroll") for (int j_ = 0; j_ < 2; ++j_) { \
    const int R_ = wn * 64 + ((QN) * 2 + j_) * 16 + lr; \
    _Pragma("unroll") for (int kk_ = 0; kk_ < 2; ++kk_) \
      DST[j_][kk_] = *(const bf16x8*)&(BUF)[R_ * 64 + (((kk_ * 4 + lg) ^ (R_ & 7)) << 3)]; \
  } \
} while (0)

#define MFMA16(BF, QM, QN) do { \
  _Pragma("unroll") for (int i_ = 0; i_ < 4; ++i_) \
  _Pragma("unroll") for (int j_ = 0; j_ < 2; ++j_) \
  _Pragma("unroll") for (int kk_ = 0; kk_ < 2; ++kk_) \
    acc[(QM) * 4 + i_][(QN) * 2 + j_] = __builtin_amdgcn_mfma_f32_16x16x32_bf16( \
        afr[i_][kk_], BF[j_][kk_], acc[(QM) * 4 + i_][(QN) * 2 + j_], 0, 0, 0); \
} while (0)

// One K-tile = 4 phases. Stage schedule (ledger-verified):
//   g0: stage B1(T+1)->OTH   g1: stage A1(T+1)->OTH
//   g2: stage A0(T+2)->CUR   g3: stage B0(T+2)->CUR
// Single vmcnt(4) at end of g3 keeps exactly {A0(T+2),B0(T+2)} in flight and
// guarantees all of tile T+1 is resident before TILE(T+1) reads it.
#define TILE(T, CURA, CURB, OTHA, OTHB) do { \
  /* g0 */ \
  LDA(0, CURA); LDB(bfr0, 0, CURB); STAGE_B(1, (T) + 1, OTHB); \
  SCHED(); BARR(); WAITLGKM(); SCHED(); \
  PRIO1(); MFMA16(bfr0, 0, 0); PRIO0(); \
  SCHED(); BARR(); SCHED(); \
  /* g1 */ \
  LDB(bfr1, 1, CURB); STAGE_A(1, (T) + 1, OTHA); \
  SCHED(); BARR(); WAITLGKM(); SCHED(); \
  PRIO1(); MFMA16(bfr1, 0, 1); PRIO0(); \
  SCHED(); BARR(); SCHED(); \
  /* g2 */ \
  LDA(1, CURA); STAGE_A(0, (T) + 2, CURA); \
  SCHED(); BARR(); WAITLGKM(); SCHED(); \
  PRIO1(); MFMA16(bfr0, 1, 0); PRIO0(); \
  SCHED(); BARR(); SCHED(); \
  /* g3 */ \
  STAGE_B(0, (T) + 2, CURB); \
  SCHED(); BARR(); SCHED(); \
  PRIO1(); MFMA16(bfr1, 1, 1); PRIO0(); \
  SCHED(); WAITVM4(); BARR(); SCHED(); \
} while (0)

template<int MODE>
__global__ __launch_bounds__(512, 2) void k_gemm256(
    const bf16* __restrict__ A, const bf16* __restrict__ BT,
    const float* __restrict__ bias, void* __restrict__ dstv,
    const float2* __restrict__ tab)
{
  __shared__ bf16 lds[2][2][256 * 64];   // [buf][A=0/B=1], 128 KB total
  const int bid = blockIdx.x;
  // XCD-aware mapping: XCD (bid&7) owns an 8-tile m-strip, sweeps bn fast.
  // Co-resident per XCD: ~4 A-panels (4MB, L2-fits) + B (8MB, L3-shared).
  const int xcd = bid & 7, idx = bid >> 3;
  const int bm = xcd * 8 + (idx >> 3), bn = idx & 7;
  const int m0 = bm * 256, n0 = bn * 256;
  const int tid = threadIdx.x;
  const int wave = tid >> 6, lane = tid & 63;
  const int wm = wave >> 2, wn = wave & 3;
  const int lr = lane & 15, lg = lane >> 4;
  const bf16* __restrict__ Ag = A;
  const bf16* __restrict__ Bg = BT;

  // staging address precompute (per-thread; element offsets fit int32)
  int srcOffA[2][2], srcOffB[2][2], ldsOffA[2][2], ldsOffB[2][2];
  {
    const int g7 = tid & 7;
#pragma unroll
    for (int u = 0; u < 2; ++u) {
      const int rl  = u * 64 + (tid >> 3);
      const int rl0 = u * 64 + wave * 8;
#pragma unroll
      for (int X = 0; X < 2; ++X) {
        const int rA  = ((rl >> 6) << 7)  | (X << 6) | (rl & 63);
        const int rA0 = ((rl0 >> 6) << 7) | (X << 6) | (rl0 & 63);
        srcOffA[u][X] = (m0 + rA) * N_D + ((g7 ^ (rA & 7)) << 3);
        ldsOffA[u][X] = rA0 * 64;
        const int rB  = ((rl >> 5) << 6)  | (X << 5) | (rl & 31);
        const int rB0 = ((rl0 >> 5) << 6) | (X << 5) | (rl0 & 31);
        srcOffB[u][X] = (n0 + rB) * N_D + ((g7 ^ (rB & 7)) << 3);
        ldsOffB[u][X] = rB0 * 64;
      }
    }
  }

  bf16* bufA0 = &lds[0][0][0];
  bf16* bufB0 = &lds[0][1][0];
  bf16* bufA1 = &lds[1][0][0];
  bf16* bufB1 = &lds[1][1][0];

  f32x4 acc[8][4];
#pragma unroll
  for (int i = 0; i < 8; ++i)
#pragma unroll
    for (int j = 0; j < 4; ++j)
      acc[i][j] = (f32x4){0.f, 0.f, 0.f, 0.f};

  bf16x8 afr[4][2], bfr0[2][2], bfr1[2][2];

  // prologue: tile0 fully + tile1 halves A0,B0 (12 loads); drain tile0 (keep 4)
  STAGE_A(0, 0, bufA0); STAGE_B(0, 0, bufB0);
  STAGE_B(1, 0, bufB0); STAGE_A(1, 0, bufA0);
  STAGE_A(0, 1, bufA1); STAGE_B(0, 1, bufB1);
  SCHED(); WAITVM4(); BARR(); SCHED();

#pragma unroll 1
  for (int t = 0; t < N_D / 64; t += 2) {
    TILE(t,     bufA0, bufB0, bufA1, bufB1);
    TILE(t + 1, bufA1, bufB1, bufA0, bufB0);
  }

  // ---- epilogue ----
#pragma unroll
  for (int i = 0; i < 8; ++i) {
#pragma unroll
    for (int r = 0; r < 4; ++r) {
      const int m = m0 + wm * 128 + i * 16 + lg * 4 + r;
#pragma unroll
      for (int j = 0; j < 4; ++j) {
        const int n = n0 + wn * 64 + j * 16 + lr;
        float v = acc[i][j][r] + bias[n];
        if (MODE == 3) {
          // fused RoPE: lanes lr, lr^1 hold adjacent d at the same row m
          float partner = __shfl_xor(v, 1);
          const int d = n & 127, l = m & 255;
          float2 cs = tab[(l << 6) | (d >> 1)];
          v = (d & 1) ? (v * cs.x + partner * cs.y) : (v * cs.x - partner * cs.y);
        }
        if (MODE == 0 || MODE == 3) {
          bf16* dst = (bf16*)dstv;
          const int b = m >> 8, l = m & 255;
          const int h = n >> 7, d = n & 127;
          dst[(((size_t)b * N_H + h) * N_L + l) * N_HD + d] = (bf16)v;
        } else if (MODE == 2) {
          bf16* dst = (bf16*)dstv;
          const int b = m >> 8, l = m & 255;
          const int h = n >> 7, d = n & 127;
          dst[(((size_t)b * N_H + h) * N_HD + d) * N_L + l] = (bf16)v;
        } else {
          float* dst = (float*)dstv;
          dst[(size_t)m * N_D + n] = v;
        }
      }
    }
  }
}

// ---------------- MFMA flash attention: one block per (b,h), 8 waves ----------------
// Q,K in [b][h][l][d] (RoPE applied). Vt in [b][h][d][l]. O to [b][l][h][d].
__global__ __launch_bounds__(512) void k_attn_mfma(
    const bf16* __restrict__ Q, const bf16* __restrict__ K,
    const bf16* __restrict__ Vt, bf16* __restrict__ O)
{
  __shared__ bf16 Kl[N_L * N_HD];   // 64KB; row j = 256B = 16 granules; granule g holds src granule g^(j&7)
  __shared__ bf16 Pl[8][16][56];    // per-wave P staging; 112B row stride

  const int bh = blockIdx.x;
  const int b = bh >> 4, h = bh & 15;
  const int tid = threadIdx.x;
  const int wave = tid >> 6, lane = tid & 63;
  const int c = lane & 15, g8 = lane >> 4;

  const bf16* Qg = Q + (size_t)bh * (N_L * N_HD);
  const bf16* Kg = K + (size_t)bh * (N_L * N_HD);
  const bf16* Vg = Vt + (size_t)bh * (N_L * N_HD);

#pragma unroll
  for (int t = 0; t < 8; ++t) {
    int idx = tid + 512 * t;            // 16B-granule index, 4096 total
    int row = idx >> 4, g = idx & 15;
    const bf16* src = Kg + row * N_HD + ((g ^ (row & 7)) << 3);
    __builtin_amdgcn_global_load_lds(
        (const __attribute__((address_space(1))) void*)src,
        (__attribute__((address_space(3))) void*)(Kl + (size_t)wave * 512 + (size_t)t * 4096),
        16, 0, 0);
  }
  __syncthreads();

  const float scale = 0.08838834764831843f;  // 1/sqrt(128)

  for (int half = 0; half < 2; ++half) {
    const int qb = half ? (15 - wave) : wave;
    const int q0 = qb * 16;

    bf16x8 qf[4];
#pragma unroll
    for (int dk = 0; dk < 4; ++dk)
      qf[dk] = *(const bf16x8*)(Qg + (size_t)(q0 + c) * N_HD + dk * 32 + g8 * 8);

    f32x4 o[8];
#pragma unroll
    for (int dj = 0; dj < 8; ++dj) o[dj] = (f32x4){0.f, 0.f, 0.f, 0.f};
    f32x4 mrow = (f32x4){-INFINITY, -INFINITY, -INFINITY, -INFINITY};
    f32x4 lrow = (f32x4){0.f, 0.f, 0.f, 0.f};

    const int nsteps = ((q0 + 15) >> 5) + 1;
    for (int js = 0; js < nsteps; ++js) {
      const int j0 = js * 32;

      bf16x8 vf[4];
#pragma unroll
      for (int dj = 0; dj < 4; ++dj)
        vf[dj] = *(const bf16x8*)(Vg + (size_t)(dj * 16 + c) * N_L + j0 + g8 * 8);

      f32x4 s0 = (f32x4){0.f, 0.f, 0.f, 0.f};
      f32x4 s1 = (f32x4){0.f, 0.f, 0.f, 0.f};
#pragma unroll
      for (int dk = 0; dk < 4; ++dk) {
        int row0 = j0 + c;
        int row1 = j0 + 16 + c;
        bf16x8 kf0 = *(const bf16x8*)(Kl + row0 * N_HD + (((dk * 4 + g8) ^ (row0 & 7)) << 3));
        bf16x8 kf1 = *(const bf16x8*)(Kl + row1 * N_HD + (((dk * 4 + g8) ^ (row1 & 7)) << 3));
        s0 = __builtin_amdgcn_mfma_f32_16x16x32_bf16(qf[dk], kf0, s0, 0, 0, 0);
        s1 = __builtin_amdgcn_mfma_f32_16x16x32_bf16(qf[dk], kf1, s1, 0, 0, 0);
      }

      // mask whenever the tile touches the upper triangle: j0+31 > q0
      f32x4 sv0, sv1;
#pragma unroll
      for (int r = 0; r < 4; ++r) { sv0[r] = s0[r] * scale; sv1[r] = s1[r] * scale; }
      if (j0 + 31 > q0) {
#pragma unroll
        for (int r = 0; r < 4; ++r) {
          int q = q0 + g8 * 4 + r;
          if (j0 + c > q)      sv0[r] = -INFINITY;
          if (j0 + 16 + c > q) sv1[r] = -INFINITY;
        }
      }

      f32x4 mx = max4(sv0, sv1);
      mx = max4(mx, shflx4(mx, 1));
      mx = max4(mx, shflx4(mx, 2));
      mx = max4(mx, shflx4(mx, 4));
      mx = max4(mx, shflx4(mx, 8));
      f32x4 mnew = max4(mrow, mx);
      f32x4 resc, p0, p1;
#pragma unroll
      for (int r = 0; r < 4; ++r) {
        resc[r] = __expf(mrow[r] - mnew[r]);
        p0[r] = __expf(sv0[r] - mnew[r]);
        p1[r] = __expf(sv1[r] - mnew[r]);
      }
      f32x4 rsum = p0 + p1;
      rsum += shflx4(rsum, 1);
      rsum += shflx4(rsum, 2);
      rsum += shflx4(rsum, 4);
      rsum += shflx4(rsum, 8);
      lrow = lrow * resc + rsum;
      mrow = mnew;
#pragma unroll
      for (int dj = 0; dj < 8; ++dj) o[dj] *= resc;

#pragma unroll
      for (int r = 0; r < 4; ++r) {
        Pl[wave][g8 * 4 + r][c] = (bf16)p0[r];
        Pl[wave][g8 * 4 + r][16 + c] = (bf16)p1[r];
      }
      bf16x8 pf = *(const bf16x8*)&Pl[wave][c][g8 * 8];

      bf16x8 vg[4];
#pragma unroll
      for (int dj = 0; dj < 4; ++dj)
        vg[dj] = *(const bf16x8*)(Vg + (size_t)((dj + 4) * 16 + c) * N_L + j0 + g8 * 8);

#pragma unroll
      for (int dj = 0; dj < 4; ++dj)
        o[dj] = __builtin_amdgcn_mfma_f32_16x16x32_bf16(pf, vf[dj], o[dj], 0, 0, 0);
#pragma unroll
      for (int dj = 0; dj < 4; ++dj)
        o[dj + 4] = __builtin_amdgcn_mfma_f32_16x16x32_bf16(pf, vg[dj], o[dj + 4], 0, 0, 0);
    }

    f32x4 inv;
#pragma unroll
    for (int r = 0; r < 4; ++r) inv[r] = 1.0f / lrow[r];
#pragma unroll
    for (int dj = 0; dj < 8; ++dj) {
      f32x4 ov = o[dj] * inv;
#pragma unroll
      for (int r = 0; r < 4; ++r) {
        int q = q0 + g8 * 4 + r;
        int d = dj * 16 + c;
        O[(((size_t)b * N_L + q) * N_H + h) * N_HD + d] = (bf16)ov[r];
      }
    }
  }
}

// ---------------- launch ----------------
extern "C" void kernel_launch(void* const* d_in, const int* in_sizes, int n_in,
                              void* d_out, int out_size, void* d_ws, size_t ws_size,
                              hipStream_t stream) {
  const float* x  = (const float*)d_in[0];
  const float* wq = (const float*)d_in[1];
  const float* bq = (const float*)d_in[2];
  const float* wk = (const float*)d_in[3];
  const float* bk = (const float*)d_in[4];
  const float* wv = (const float*)d_in[5];
  const float* bv = (const float*)d_in[6];
  const float* wo = (const float*)d_in[7];
  const float* bo = (const float*)d_in[8];

  char* ws = (char*)d_ws;
  const size_t WSZ = (size_t)N_D * N_D * sizeof(bf16);    // 8 MB per transposed weight
  const size_t XSZ = (size_t)M_TOT * N_D * sizeof(bf16);  // 64 MB per activation tensor
  bf16* wqT = (bf16*)(ws);
  bf16* wkT = (bf16*)(ws + WSZ);
  bf16* wvT = (bf16*)(ws + 2 * WSZ);
  bf16* woT = (bf16*)(ws + 3 * WSZ);
  bf16* xb  = (bf16*)(ws + 4 * WSZ);
  bf16* Qb  = (bf16*)(ws + 4 * WSZ + XSZ);
  bf16* Kb  = (bf16*)(ws + 4 * WSZ + 2 * XSZ);
  bf16* Vb  = (bf16*)(ws + 4 * WSZ + 3 * XSZ);  // holds V^T: [b][h][d][l]
  bf16* Ob  = (bf16*)(ws + 4 * WSZ + 4 * XSZ);
  float2* tab = (float2*)(ws + 4 * WSZ + 5 * XSZ);

  k_cast_x<<<2048, 256, 0, stream>>>(x, xb, M_TOT * N_D / 4);
  dim3 tb(32, 32), tg(64, 64);
  k_transpose_w<<<tg, tb, 0, stream>>>(wq, wqT);
  k_transpose_w<<<tg, tb, 0, stream>>>(wk, wkT);
  k_transpose_w<<<tg, tb, 0, stream>>>(wv, wvT);
  k_transpose_w<<<tg, tb, 0, stream>>>(wo, woT);
  k_trig<<<64, 256, 0, stream>>>(tab);

  const int grid = (M_TOT / 256) * (N_D / 256);  // 512
  k_gemm256<3><<<grid, 512, 0, stream>>>(xb, wqT, bq, Qb, tab);   // Q proj + RoPE
  k_gemm256<3><<<grid, 512, 0, stream>>>(xb, wkT, bk, Kb, tab);   // K proj + RoPE
  k_gemm256<2><<<grid, 512, 0, stream>>>(xb, wvT, bv, Vb, tab);   // V proj, transposed

  k_attn_mfma<<<1024, 512, 0, stream>>>(Qb, Kb, Vb, Ob);
  k_gemm256<1><<<grid, 512, 0, stream>>>(Ob, woT, bo, d_out, tab);
}

// Round 7
// 676.126 us; speedup vs baseline: 5.5577x; 1.0051x over previous
//
#include <hip/hip_runtime.h>
#include <math.h>

typedef __bf16 bf16;
typedef float f32x4 __attribute__((ext_vector_type(4)));
typedef bf16  bf16x4 __attribute__((ext_vector_type(4)));
typedef bf16  bf16x8 __attribute__((ext_vector_type(8)));

#define N_B  64
#define N_L  256
#define N_H  16
#define N_D  2048
#define N_HD 128
#define M_TOT (N_B * N_L)   // 16384

static __device__ __forceinline__ float bfbits_lo(unsigned u) {
  union { unsigned u; float f; } c; c.u = u << 16; return c.f;
}
static __device__ __forceinline__ float bfbits_hi(unsigned u) {
  union { unsigned u; float f; } c; c.u = u & 0xffff0000u; return c.f;
}

static __device__ __forceinline__ f32x4 shflx4(f32x4 v, int m) {
  f32x4 r;
  r[0] = __shfl_xor(v[0], m);
  r[1] = __shfl_xor(v[1], m);
  r[2] = __shfl_xor(v[2], m);
  r[3] = __shfl_xor(v[3], m);
  return r;
}
static __device__ __forceinline__ f32x4 max4(f32x4 a, f32x4 b) {
  f32x4 r;
  r[0] = fmaxf(a[0], b[0]); r[1] = fmaxf(a[1], b[1]);
  r[2] = fmaxf(a[2], b[2]); r[3] = fmaxf(a[3], b[3]);
  return r;
}

// ---------------- prep kernels ----------------
__global__ void k_cast_x(const float* __restrict__ x, bf16* __restrict__ xb, int n4) {
  int i = blockIdx.x * blockDim.x + threadIdx.x;
  int st = gridDim.x * blockDim.x;
  for (; i < n4; i += st) {
    float4 v = ((const float4*)x)[i];
    bf16x4 o;
    o[0] = (bf16)v.x; o[1] = (bf16)v.y; o[2] = (bf16)v.z; o[3] = (bf16)v.w;
    ((bf16x4*)xb)[i] = o;
  }
}

__global__ void k_transpose_w(const float* __restrict__ w, bf16* __restrict__ wt) {
  __shared__ float t[32][33];
  int n0 = blockIdx.x * 32, k0 = blockIdx.y * 32;
  t[threadIdx.y][threadIdx.x] = w[(size_t)(k0 + threadIdx.y) * N_D + n0 + threadIdx.x];
  __syncthreads();
  wt[(size_t)(n0 + threadIdx.y) * N_D + k0 + threadIdx.x] = (bf16)t[threadIdx.x][threadIdx.y];
}

__global__ void k_trig(float2* __restrict__ tab) {
  int idx = blockIdx.x * blockDim.x + threadIdx.x;
  if (idx < N_L * (N_HD / 2)) {
    int l = idx >> 6, i = idx & 63;
    float ang = (float)l * powf(10000.0f, -(float)(2 * i) / 128.0f);
    tab[idx].x = cosf(ang);
    tab[idx].y = sinf(ang);
  }
}

// ---------------- 256x256 read-ahead MFMA GEMM ----------------
// C[m][n] = sum_k A[m][k] * BT[n][k] + bias[n]
// 8 waves (2M x 4N), per-wave 128x64, BK=64, dbuf 128KB LDS.
// Pipeline: each phase {stage 2 gloads; issue NEXT chunk's ds_reads;
// counted lgkmcnt for PREV chunk; 16 MFMA; 1 barrier}. Chunks = (m-half, k-slice),
// ping-pong reg banks. vmcnt(6)@P1, vmcnt(4)@P3 (never 0). Ledger-verified.

#define GLOAD(GP, LP) __builtin_amdgcn_global_load_lds( \
    (const __attribute__((address_space(1))) void*)(GP), \
    (__attribute__((address_space(3))) void*)(LP), 16, 0, 0)
#define BARR()  __builtin_amdgcn_s_barrier()
#define SCHED() __builtin_amdgcn_sched_barrier(0)
#define PRIO1() __builtin_amdgcn_s_setprio(1)
#define PRIO0() __builtin_amdgcn_s_setprio(0)
#define WAITLGKM4() asm volatile("s_waitcnt lgkmcnt(4)" ::: "memory")
#define WAITLGKM8() asm volatile("s_waitcnt lgkmcnt(8)" ::: "memory")
#define WAITVM4()   asm volatile("s_waitcnt vmcnt(4)" ::: "memory")
#define WAITVM6()   asm volatile("s_waitcnt vmcnt(6)" ::: "memory")

// KT masked &31 so tail tiles stage in-range (never-read) data.
#define STAGE_A(X, KT, BUF) do { \
  GLOAD(Ag + (size_t)srcOffA[0][X] + (size_t)((KT) & 31) * 64, (BUF) + ldsOffA[0][X]); \
  GLOAD(Ag + (size_t)srcOffA[1][X] + (size_t)((KT) & 31) * 64, (BUF) + ldsOffA[1][X]); \
} while (0)
#define STAGE_B(X, KT, BUF) do { \
  GLOAD(Bg + (size_t)srcOffB[0][X] + (size_t)((KT) & 31) * 64, (BUF) + ldsOffB[0][X]); \
  GLOAD(Bg + (size_t)srcOffB[1][X] + (size_t)((KT) & 31) * 64, (BUF) + ldsOffB[1][X]); \
} while (0)

// A chunk (m-half MH, k-slice KK): 4 x ds_read_b128
#define RD_A(DST, MH, KK, BUF) do { \
  _Pragma("unroll") for (int i_ = 0; i_ < 4; ++i_) { \
    const int R_ = wm * 128 + (MH) * 64 + i_ * 16 + lr; \
    DST[i_] = *(const bf16x8*)&(BUF)[R_ * 64 + ((((KK) * 4 + lg) ^ (R_ & 7)) << 3)]; \
  } \
} while (0)
// B chunk (k-slice KK): 4 x ds_read_b128 (all 4 n-frags of the wave)
#define RD_B(DST, KK, BUF) do { \
  _Pragma("unroll") for (int j_ = 0; j_ < 4; ++j_) { \
    const int R_ = wn * 64 + j_ * 16 + lr; \
    DST[j_] = *(const bf16x8*)&(BUF)[R_ * 64 + ((((KK) * 4 + lg) ^ (R_ & 7)) << 3)]; \
  } \
} while (0)

// 16 independent MFMAs: chunk (MH, k) x all 4 n-frags
#define MFMA16(AB, BB, MH) do { \
  _Pragma("unroll") for (int i_ = 0; i_ < 4; ++i_) \
  _Pragma("unroll") for (int j_ = 0; j_ < 4; ++j_) \
    acc[(MH) * 4 + i_][j_] = __builtin_amdgcn_mfma_f32_16x16x32_bf16( \
        AB[i_], BB[j_], acc[(MH) * 4 + i_][j_], 0, 0, 0); \
} while (0)

// Chunk order c0=(m0,k0) c1=(m0,k1) c2=(m1,k0) c3=(m1,k1).
// Banks: c0->A0b, c1->A1b, c2->A0b, c3->A1b; B0b=k0, B1b=k1.
// Phase p MFMAs chunk p using reads issued at phase p-1.
// Stage slots: B1(t+1)@P0, A1(t+1)@P1, A0(t+2)@P2, B0(t+2)@P3.
// WAR distances all >= 2 barriers; residency: vm(6)@P1, vm(4)@P3.
#define TILE(T, CURA, CURB, OTHA, OTHB) do { \
  /* P0 */ \
  STAGE_B(1, (T) + 1, OTHB); \
  RD_A(A1b, 0, 1, CURA); RD_B(B1b, 1, CURB); \
  SCHED(); WAITLGKM8(); SCHED(); \
  PRIO1(); MFMA16(A0b, B0b, 0); PRIO0(); \
  SCHED(); BARR(); \
  /* P1 */ \
  WAITVM6(); \
  STAGE_A(1, (T) + 1, OTHA); \
  RD_A(A0b, 1, 0, CURA); \
  SCHED(); WAITLGKM4(); SCHED(); \
  PRIO1(); MFMA16(A1b, B1b, 0); PRIO0(); \
  SCHED(); BARR(); \
  /* P2 */ \
  STAGE_A(0, (T) + 2, CURA); \
  RD_A(A1b, 1, 1, CURA); \
  SCHED(); WAITLGKM4(); SCHED(); \
  PRIO1(); MFMA16(A0b, B0b, 1); PRIO0(); \
  SCHED(); BARR(); \
  /* P3 */ \
  WAITVM4(); \
  STAGE_B(0, (T) + 2, CURB); \
  RD_A(A0b, 0, 0, OTHA); RD_B(B0b, 0, OTHB); \
  SCHED(); WAITLGKM8(); SCHED(); \
  PRIO1(); MFMA16(A1b, B1b, 1); PRIO0(); \
  SCHED(); BARR(); \
} while (0)

template<int MODE>
__global__ __launch_bounds__(512, 2) void k_gemm256(
    const bf16* __restrict__ A, const bf16* __restrict__ BT,
    const float* __restrict__ bias, void* __restrict__ dstv,
    const float2* __restrict__ tab)
{
  __shared__ bf16 lds[2][2][256 * 64];   // [buf][A=0/B=1], 128 KB total
  const int bid = blockIdx.x;
  // XCD-aware mapping: XCD (bid&7) owns an 8-tile m-strip, sweeps bn fast.
  const int xcd = bid & 7, idx = bid >> 3;
  const int bm = xcd * 8 + (idx >> 3), bn = idx & 7;
  const int m0 = bm * 256, n0 = bn * 256;
  const int tid = threadIdx.x;
  const int wave = tid >> 6, lane = tid & 63;
  const int wm = wave >> 2, wn = wave & 3;
  const int lr = lane & 15, lg = lane >> 4;
  const bf16* __restrict__ Ag = A;
  const bf16* __restrict__ Bg = BT;

  // staging address precompute
  int srcOffA[2][2], srcOffB[2][2], ldsOffA[2][2], ldsOffB[2][2];
  {
    const int g7 = tid & 7;
#pragma unroll
    for (int u = 0; u < 2; ++u) {
      const int rl  = u * 64 + (tid >> 3);
      const int rl0 = u * 64 + wave * 8;
#pragma unroll
      for (int X = 0; X < 2; ++X) {
        const int rA  = ((rl >> 6) << 7)  | (X << 6) | (rl & 63);
        const int rA0 = ((rl0 >> 6) << 7) | (X << 6) | (rl0 & 63);
        srcOffA[u][X] = (m0 + rA) * N_D + ((g7 ^ (rA & 7)) << 3);
        ldsOffA[u][X] = rA0 * 64;
        const int rB  = ((rl >> 5) << 6)  | (X << 5) | (rl & 31);
        const int rB0 = ((rl0 >> 5) << 6) | (X << 5) | (rl0 & 31);
        srcOffB[u][X] = (n0 + rB) * N_D + ((g7 ^ (rB & 7)) << 3);
        ldsOffB[u][X] = rB0 * 64;
      }
    }
  }

  bf16* bufA0 = &lds[0][0][0];
  bf16* bufB0 = &lds[0][1][0];
  bf16* bufA1 = &lds[1][0][0];
  bf16* bufB1 = &lds[1][1][0];

  f32x4 acc[8][4];
#pragma unroll
  for (int i = 0; i < 8; ++i)
#pragma unroll
    for (int j = 0; j < 4; ++j)
      acc[i][j] = (f32x4){0.f, 0.f, 0.f, 0.f};

  bf16x8 A0b[4], A1b[4], B0b[4], B1b[4];

  // prologue: tile0 fully (8) + tile1 A0,B0 (4); retire tile0; preload c0/k0 regs
  STAGE_A(0, 0, bufA0); STAGE_B(0, 0, bufB0);
  STAGE_B(1, 0, bufB0); STAGE_A(1, 0, bufA0);
  STAGE_A(0, 1, bufA1); STAGE_B(0, 1, bufB1);
  SCHED(); WAITVM4(); BARR(); SCHED();
  RD_A(A0b, 0, 0, bufA0); RD_B(B0b, 0, bufB0);
  SCHED();

#pragma unroll 1
  for (int t = 0; t < N_D / 64; t += 2) {
    TILE(t,     bufA0, bufB0, bufA1, bufB1);
    TILE(t + 1, bufA1, bufB1, bufA0, bufB0);
  }

  // ---- epilogue ----
#pragma unroll
  for (int i = 0; i < 8; ++i) {
#pragma unroll
    for (int r = 0; r < 4; ++r) {
      const int m = m0 + wm * 128 + i * 16 + lg * 4 + r;
#pragma unroll
      for (int j = 0; j < 4; ++j) {
        const int n = n0 + wn * 64 + j * 16 + lr;
        float v = acc[i][j][r] + bias[n];
        if (MODE == 3) {
          // fused RoPE: lanes lr, lr^1 hold adjacent d at the same row m
          float partner = __shfl_xor(v, 1);
          const int d = n & 127, l = m & 255;
          float2 cs = tab[(l << 6) | (d >> 1)];
          v = (d & 1) ? (v * cs.x + partner * cs.y) : (v * cs.x - partner * cs.y);
        }
        if (MODE == 0 || MODE == 3) {
          bf16* dst = (bf16*)dstv;
          const int b = m >> 8, l = m & 255;
          const int h = n >> 7, d = n & 127;
          dst[(((size_t)b * N_H + h) * N_L + l) * N_HD + d] = (bf16)v;
        } else if (MODE == 2) {
          bf16* dst = (bf16*)dstv;
          const int b = m >> 8, l = m & 255;
          const int h = n >> 7, d = n & 127;
          dst[(((size_t)b * N_H + h) * N_HD + d) * N_L + l] = (bf16)v;
        } else {
          float* dst = (float*)dstv;
          dst[(size_t)m * N_D + n] = v;
        }
      }
    }
  }
}

// ---------------- MFMA flash attention: one block per (b,h), 8 waves ----------------
// Q,K in [b][h][l][d] (RoPE applied). Vt in [b][h][d][l]. O to [b][l][h][d].
__global__ __launch_bounds__(512) void k_attn_mfma(
    const bf16* __restrict__ Q, const bf16* __restrict__ K,
    const bf16* __restrict__ Vt, bf16* __restrict__ O)
{
  __shared__ bf16 Kl[N_L * N_HD];   // 64KB; row j = 256B = 16 granules; granule g holds src granule g^(j&7)
  __shared__ bf16 Pl[8][16][56];    // per-wave P staging; 112B row stride

  const int bh = blockIdx.x;
  const int b = bh >> 4, h = bh & 15;
  const int tid = threadIdx.x;
  const int wave = tid >> 6, lane = tid & 63;
  const int c = lane & 15, g8 = lane >> 4;

  const bf16* Qg = Q + (size_t)bh * (N_L * N_HD);
  const bf16* Kg = K + (size_t)bh * (N_L * N_HD);
  const bf16* Vg = Vt + (size_t)bh * (N_L * N_HD);

#pragma unroll
  for (int t = 0; t < 8; ++t) {
    int idx = tid + 512 * t;            // 16B-granule index, 4096 total
    int row = idx >> 4, g = idx & 15;
    const bf16* src = Kg + row * N_HD + ((g ^ (row & 7)) << 3);
    __builtin_amdgcn_global_load_lds(
        (const __attribute__((address_space(1))) void*)src,
        (__attribute__((address_space(3))) void*)(Kl + (size_t)wave * 512 + (size_t)t * 4096),
        16, 0, 0);
  }
  __syncthreads();

  const float scale = 0.08838834764831843f;  // 1/sqrt(128)

  for (int half = 0; half < 2; ++half) {
    const int qb = half ? (15 - wave) : wave;
    const int q0 = qb * 16;

    bf16x8 qf[4];
#pragma unroll
    for (int dk = 0; dk < 4; ++dk)
      qf[dk] = *(const bf16x8*)(Qg + (size_t)(q0 + c) * N_HD + dk * 32 + g8 * 8);

    f32x4 o[8];
#pragma unroll
    for (int dj = 0; dj < 8; ++dj) o[dj] = (f32x4){0.f, 0.f, 0.f, 0.f};
    f32x4 mrow = (f32x4){-INFINITY, -INFINITY, -INFINITY, -INFINITY};
    f32x4 lrow = (f32x4){0.f, 0.f, 0.f, 0.f};

    const int nsteps = ((q0 + 15) >> 5) + 1;
    for (int js = 0; js < nsteps; ++js) {
      const int j0 = js * 32;

      bf16x8 vf[4];
#pragma unroll
      for (int dj = 0; dj < 4; ++dj)
        vf[dj] = *(const bf16x8*)(Vg + (size_t)(dj * 16 + c) * N_L + j0 + g8 * 8);

      f32x4 s0 = (f32x4){0.f, 0.f, 0.f, 0.f};
      f32x4 s1 = (f32x4){0.f, 0.f, 0.f, 0.f};
#pragma unroll
      for (int dk = 0; dk < 4; ++dk) {
        int row0 = j0 + c;
        int row1 = j0 + 16 + c;
        bf16x8 kf0 = *(const bf16x8*)(Kl + row0 * N_HD + (((dk * 4 + g8) ^ (row0 & 7)) << 3));
        bf16x8 kf1 = *(const bf16x8*)(Kl + row1 * N_HD + (((dk * 4 + g8) ^ (row1 & 7)) << 3));
        s0 = __builtin_amdgcn_mfma_f32_16x16x32_bf16(qf[dk], kf0, s0, 0, 0, 0);
        s1 = __builtin_amdgcn_mfma_f32_16x16x32_bf16(qf[dk], kf1, s1, 0, 0, 0);
      }

      // mask whenever the tile touches the upper triangle: j0+31 > q0
      f32x4 sv0, sv1;
#pragma unroll
      for (int r = 0; r < 4; ++r) { sv0[r] = s0[r] * scale; sv1[r] = s1[r] * scale; }
      if (j0 + 31 > q0) {
#pragma unroll
        for (int r = 0; r < 4; ++r) {
          int q = q0 + g8 * 4 + r;
          if (j0 + c > q)      sv0[r] = -INFINITY;
          if (j0 + 16 + c > q) sv1[r] = -INFINITY;
        }
      }

      f32x4 mx = max4(sv0, sv1);
      mx = max4(mx, shflx4(mx, 1));
      mx = max4(mx, shflx4(mx, 2));
      mx = max4(mx, shflx4(mx, 4));
      mx = max4(mx, shflx4(mx, 8));
      f32x4 mnew = max4(mrow, mx);
      f32x4 resc, p0, p1;
#pragma unroll
      for (int r = 0; r < 4; ++r) {
        resc[r] = __expf(mrow[r] - mnew[r]);
        p0[r] = __expf(sv0[r] - mnew[r]);
        p1[r] = __expf(sv1[r] - mnew[r]);
      }
      f32x4 rsum = p0 + p1;
      rsum += shflx4(rsum, 1);
      rsum += shflx4(rsum, 2);
      rsum += shflx4(rsum, 4);
      rsum += shflx4(rsum, 8);
      lrow = lrow * resc + rsum;
      mrow = mnew;
#pragma unroll
      for (int dj = 0; dj < 8; ++dj) o[dj] *= resc;

#pragma unroll
      for (int r = 0; r < 4; ++r) {
        Pl[wave][g8 * 4 + r][c] = (bf16)p0[r];
        Pl[wave][g8 * 4 + r][16 + c] = (bf16)p1[r];
      }
      bf16x8 pf = *(const bf16x8*)&Pl[wave][c][g8 * 8];

      bf16x8 vg[4];
#pragma unroll
      for (int dj = 0; dj < 4; ++dj)
        vg[dj] = *(const bf16x8*)(Vg + (size_t)((dj + 4) * 16 + c) * N_L + j0 + g8 * 8);

#pragma unroll
      for (int dj = 0; dj < 4; ++dj)
        o[dj] = __builtin_amdgcn_mfma_f32_16x16x32_bf16(pf, vf[dj], o[dj], 0, 0, 0);
#pragma unroll
      for (int dj = 0; dj < 4; ++dj)
        o[dj + 4] = __builtin_amdgcn_mfma_f32_16x16x32_bf16(pf, vg[dj], o[dj + 4], 0, 0, 0);
    }

    f32x4 inv;
#pragma unroll
    for (int r = 0; r < 4; ++r) inv[r] = 1.0f / lrow[r];
#pragma unroll
    for (int dj = 0; dj < 8; ++dj) {
      f32x4 ov = o[dj] * inv;
#pragma unroll
      for (int r = 0; r < 4; ++r) {
        int q = q0 + g8 * 4 + r;
        int d = dj * 16 + c;
        O[(((size_t)b * N_L + q) * N_H + h) * N_HD + d] = (bf16)ov[r];
      }
    }
  }
}

// ---------------- launch ----------------
extern "C" void kernel_launch(void* const* d_in, const int* in_sizes, int n_in,
                              void* d_out, int out_size, void* d_ws, size_t ws_size,
                              hipStream_t stream) {
  const float* x  = (const float*)d_in[0];
  const float* wq = (const float*)d_in[1];
  const float* bq = (const float*)d_in[2];
  const float* wk = (const float*)d_in[3];
  const float* bk = (const float*)d_in[4];
  const float* wv = (const float*)d_in[5];
  const float* bv = (const float*)d_in[6];
  const float* wo = (const float*)d_in[7];
  const float* bo = (const float*)d_in[8];

  char* ws = (char*)d_ws;
  const size_t WSZ = (size_t)N_D * N_D * sizeof(bf16);    // 8 MB per transposed weight
  const size_t XSZ = (size_t)M_TOT * N_D * sizeof(bf16);  // 64 MB per activation tensor
  bf16* wqT = (bf16*)(ws);
  bf16* wkT = (bf16*)(ws + WSZ);
  bf16* wvT = (bf16*)(ws + 2 * WSZ);
  bf16* woT = (bf16*)(ws + 3 * WSZ);
  bf16* xb  = (bf16*)(ws + 4 * WSZ);
  bf16* Qb  = (bf16*)(ws + 4 * WSZ + XSZ);
  bf16* Kb  = (bf16*)(ws + 4 * WSZ + 2 * XSZ);
  bf16* Vb  = (bf16*)(ws + 4 * WSZ + 3 * XSZ);  // holds V^T: [b][h][d][l]
  bf16* Ob  = (bf16*)(ws + 4 * WSZ + 4 * XSZ);
  float2* tab = (float2*)(ws + 4 * WSZ + 5 * XSZ);

  k_cast_x<<<2048, 256, 0, stream>>>(x, xb, M_TOT * N_D / 4);
  dim3 tb(32, 32), tg(64, 64);
  k_transpose_w<<<tg, tb, 0, stream>>>(wq, wqT);
  k_transpose_w<<<tg, tb, 0, stream>>>(wk, wkT);
  k_transpose_w<<<tg, tb, 0, stream>>>(wv, wvT);
  k_transpose_w<<<tg, tb, 0, stream>>>(wo, woT);
  k_trig<<<64, 256, 0, stream>>>(tab);

  const int grid = (M_TOT / 256) * (N_D / 256);  // 512
  k_gemm256<3><<<grid, 512, 0, stream>>>(xb, wqT, bq, Qb, tab);   // Q proj + RoPE
  k_gemm256<3><<<grid, 512, 0, stream>>>(xb, wkT, bk, Kb, tab);   // K proj + RoPE
  k_gemm256<2><<<grid, 512, 0, stream>>>(xb, wvT, bv, Vb, tab);   // V proj, transposed

  k_attn_mfma<<<1024, 512, 0, stream>>>(Qb, Kb, Vb, Ob);
  k_gemm256<1><<<grid, 512, 0, stream>>>(Ob, woT, bo, d_out, tab);
}